// Round 3
// baseline (313.005 us; speedup 1.0000x reference)
//
#include <hip/hip_runtime.h>
#include <hip/hip_bf16.h>

#define DEVI __device__ __forceinline__

typedef __attribute__((ext_vector_type(8))) short short8;
typedef __attribute__((ext_vector_type(8))) unsigned short ushort8;
typedef __attribute__((ext_vector_type(4))) float f32x4;

// problem constants
static constexpr int BB = 32, TT = 64, KIN = 4894, KINP = 4896;
static constexpr int E = 128, NG = 768;

DEVI unsigned short f2bf(float f) {
    union { float f; unsigned u; } v; v.f = f;
    unsigned r = v.u + 0x7fffu + ((v.u >> 16) & 1u);
    return (unsigned short)(r >> 16);
}
DEVI float sigm(float x) { return __builtin_amdgcn_rcpf(1.f + __expf(-x)); }
DEVI float tanh_(float x) { return 1.f - 2.f * __builtin_amdgcn_rcpf(__expf(2.f * x) + 1.f); }

// ---------------- prep: weight casts / padding only ----------------
__global__ void prep_kernel(const float* __restrict__ Wemb,
                            const float* __restrict__ Wih_a, const float* __restrict__ Wih_b,
                            const float* __restrict__ Whh_a, const float* __restrict__ Whh_b,
                            const float* __restrict__ Wbeta,
                            unsigned short* __restrict__ wembbf,
                            unsigned short* __restrict__ wihbf, unsigned short* __restrict__ whhbf,
                            unsigned short* __restrict__ wbetabf, float* __restrict__ col128) {
    int job = blockIdx.x * blockDim.x + threadIdx.x;
    const int JWE = 128 * 612, JWIH = 768 * 16, JWHH = 768 * 16, JWB = 128 * 16, JCOL = 96;
    if (job < JWE) {
        int row = job / 612, c8 = (job % 612) * 8;
        ushort8 v;
        #pragma unroll
        for (int jj = 0; jj < 8; ++jj) { int c = c8 + jj; v[jj] = (c < KIN) ? f2bf(Wemb[(long)row * KIN + c]) : (unsigned short)0; }
        *(ushort8*)(wembbf + (long)row * KINP + c8) = v;
        return;
    }
    job -= JWE;
    if (job < JWIH) {
        int g = job / 16, c8 = (job % 16) * 8;
        const float* src = (g < 384) ? (Wih_a + (long)g * 129) : (Wih_b + (long)(g - 384) * 129);
        ushort8 v;
        #pragma unroll
        for (int jj = 0; jj < 8; ++jj) v[jj] = f2bf(src[c8 + jj]);
        *(ushort8*)(wihbf + (long)g * 128 + c8) = v;
        return;
    }
    job -= JWIH;
    if (job < JWHH) {
        int g = job / 16, c8 = (job % 16) * 8;
        const float* src = (g < 384) ? (Whh_a + (long)g * 128) : (Whh_b + (long)(g - 384) * 128);
        ushort8 v;
        #pragma unroll
        for (int jj = 0; jj < 8; ++jj) v[jj] = f2bf(src[c8 + jj]);
        *(ushort8*)(whhbf + (long)g * 128 + c8) = v;
        return;
    }
    job -= JWHH;
    if (job < JWB) {
        int e = job / 16, c8 = (job % 16) * 8;
        ushort8 v;
        #pragma unroll
        for (int jj = 0; jj < 8; ++jj) v[jj] = f2bf(Wbeta[(long)e * 128 + c8 + jj]);
        *(ushort8*)(wbetabf + (long)e * 128 + c8) = v;
        return;
    }
    job -= JWB;
    if (job < JCOL) {
        int g0 = job * 8;
        #pragma unroll
        for (int jj = 0; jj < 8; ++jj) {
            int g = g0 + jj;
            col128[g] = (g < 384) ? Wih_a[(long)g * 129 + 128] : Wih_b[(long)(g - 384) * 129 + 128];
        }
    }
}

// ---------------- emb = x @ Wemb^T  (x f32 loaded directly, converted in-reg) ----------------
__global__ __launch_bounds__(256) void emb_gemm(const float* __restrict__ x,
                                                const unsigned short* __restrict__ wembbf,
                                                float* __restrict__ emb, unsigned short* __restrict__ embbf) {
    const int m0 = blockIdx.x * 16;
    const int w = threadIdx.x >> 6, l = threadIdx.x & 63, lr = l & 15, lo = l >> 4;
    const int n0 = (2 * w) * 16 + lr, n1 = (2 * w + 1) * 16 + lr;
    const float* xrow = x + (long)(m0 + lr) * KIN;
    f32x4 acc0 = {0, 0, 0, 0}, acc1 = {0, 0, 0, 0};
    #pragma unroll 4
    for (int kt = 0; kt < 152; ++kt) {
        int k = kt * 32 + lo * 8;
        float2 x0 = *(const float2*)(xrow + k);
        float2 x1 = *(const float2*)(xrow + k + 2);
        float2 x2 = *(const float2*)(xrow + k + 4);
        float2 x3 = *(const float2*)(xrow + k + 6);
        short8 a;
        a[0] = (short)f2bf(x0.x); a[1] = (short)f2bf(x0.y);
        a[2] = (short)f2bf(x1.x); a[3] = (short)f2bf(x1.y);
        a[4] = (short)f2bf(x2.x); a[5] = (short)f2bf(x2.y);
        a[6] = (short)f2bf(x3.x); a[7] = (short)f2bf(x3.y);
        short8 b0 = *(const short8*)(wembbf + (long)n0 * KINP + k);
        short8 b1 = *(const short8*)(wembbf + (long)n1 * KINP + k);
        acc0 = __builtin_amdgcn_mfma_f32_16x16x32_bf16(a, b0, acc0, 0, 0, 0);
        acc1 = __builtin_amdgcn_mfma_f32_16x16x32_bf16(a, b1, acc1, 0, 0, 0);
    }
    { // tail k-tile (kt=152): guard the last 2 columns (4894,4895)
        int k = 4864 + lo * 8;
        short8 a;
        #pragma unroll
        for (int jj = 0; jj < 8; ++jj) { int c = k + jj; a[jj] = (c < KIN) ? (short)f2bf(xrow[c]) : (short)0; }
        short8 b0 = *(const short8*)(wembbf + (long)n0 * KINP + k);
        short8 b1 = *(const short8*)(wembbf + (long)n1 * KINP + k);
        acc0 = __builtin_amdgcn_mfma_f32_16x16x32_bf16(a, b0, acc0, 0, 0, 0);
        acc1 = __builtin_amdgcn_mfma_f32_16x16x32_bf16(a, b1, acc1, 0, 0, 0);
    }
    #pragma unroll
    for (int r = 0; r < 4; ++r) {
        int m = m0 + lo * 4 + r;
        emb[(long)m * E + n0] = acc0[r];
        emb[(long)m * E + n1] = acc1[r];
        embbf[(long)m * E + n0] = f2bf(acc0[r]);
        embbf[(long)m * E + n1] = f2bf(acc1[r]);
    }
}

// ---------------- Gi3 = temb @ Wih^T + bih + bhh(r,z), repacked [tok][gru][u][r,z,n,pad] ----------------
__global__ __launch_bounds__(256) void gi_gemm(const unsigned short* __restrict__ embbf,
                                               const unsigned short* __restrict__ wihbf,
                                               const float* __restrict__ t,
                                               const float* __restrict__ bih_a, const float* __restrict__ bih_b,
                                               const float* __restrict__ bhh_a, const float* __restrict__ bhh_b,
                                               const float* __restrict__ col128, float* __restrict__ Gi3) {
    const int m0 = blockIdx.x * 32;
    const int w = threadIdx.x >> 6, l = threadIdx.x & 63, lr = l & 15, lo = l >> 4;
    f32x4 acc[2][12];
    #pragma unroll
    for (int mt = 0; mt < 2; ++mt)
        #pragma unroll
        for (int nl = 0; nl < 12; ++nl) acc[mt][nl] = (f32x4){0, 0, 0, 0};
    #pragma unroll
    for (int kt = 0; kt < 4; ++kt) {
        int k = kt * 32 + lo * 8;
        short8 a0 = *(const short8*)(embbf + (long)(m0 + lr) * E + k);
        short8 a1 = *(const short8*)(embbf + (long)(m0 + 16 + lr) * E + k);
        #pragma unroll
        for (int nl = 0; nl < 12; ++nl) {
            int n = (w * 12 + nl) * 16 + lr;
            short8 bf = *(const short8*)(wihbf + (long)n * 128 + k);
            acc[0][nl] = __builtin_amdgcn_mfma_f32_16x16x32_bf16(a0, bf, acc[0][nl], 0, 0, 0);
            acc[1][nl] = __builtin_amdgcn_mfma_f32_16x16x32_bf16(a1, bf, acc[1][nl], 0, 0, 0);
        }
    }
    #pragma unroll
    for (int mt = 0; mt < 2; ++mt)
        #pragma unroll
        for (int nl = 0; nl < 12; ++nl) {
            int n = (w * 12 + nl) * 16 + lr;      // 0..767
            int gru = (n >= 384) ? 1 : 0;
            int nn = n - gru * 384;
            int gt = nn >> 7, u = nn & 127;
            float bias = (gru ? bih_b[nn] : bih_a[nn]);
            if (gt < 2) bias += (gru ? bhh_b[nn] : bhh_a[nn]);
            float cw = col128[n];
            #pragma unroll
            for (int r = 0; r < 4; ++r) {
                int tok = m0 + mt * 16 + lo * 4 + r;
                Gi3[((long)(tok * 2 + gru) * 128 + u) * 4 + gt] = acc[mt][nl][r] + bias + t[tok] * cw;
            }
        }
}

// ---------------- recurrence + online-softmax attention (1 barrier / step) ----------------
// 128 blocks = (i 0..63) x (q 0..1); 16 chains/block; 8 waves; gru = w>>2.
// Pipeline: iter k computes gh_k/gates_k (H_{k-1}->H_k), beta/score of H_{k-1} (lag 1),
// attention accumulation of step k-2 (lag 2). Double-buffered Hbf -> single barrier.
// launch_bounds(512, 1): 8 waves/CU -> 2 waves/SIMD -> 256-VGPR budget (the ~230-reg
// working set spilled to scratch at the default 128-VGPR cap: 74 MB FETCH, 8 MB WRITE).
__global__ __launch_bounds__(512, 1) void retain_rec(
    const unsigned short* __restrict__ whhbf, const unsigned short* __restrict__ wbetabf,
    const float* __restrict__ Gi3, const float* __restrict__ emb,
    const float* __restrict__ bhh_a, const float* __restrict__ bhh_b,
    const float* __restrict__ w_alpha, const float* __restrict__ b_alpha,
    const float* __restrict__ b_beta, const float* __restrict__ Wout,
    const float* __restrict__ b_out, const int* __restrict__ lengths,
    float* __restrict__ out) {
    const int tid = threadIdx.x;
    const int w = tid >> 6, l = tid & 63, lr = l & 15, lo = l >> 4;
    const int i = blockIdx.x >> 1, q = blockIdx.x & 1;
    const int gru = w >> 2;
    const int ubase = (w & 3) * 32;

    __shared__ __align__(16) unsigned short Hbf[2][2][16][128]; // [buf][gru][c][u ^ ((c&7)*8)]
    __shared__ float fac_s[2][16], p_s[2][16];
    __shared__ float l_s[16];
    __shared__ float red_s[16][64];

    for (int idx = tid; idx < 2 * 16 * 128; idx += 512) (&Hbf[0][0][0][0])[idx] = 0; // H_{-1}=0

    // persistent Whh B-fragments
    short8 Wf[6][4];
    #pragma unroll
    for (int utl = 0; utl < 2; ++utl)
        #pragma unroll
        for (int gt = 0; gt < 3; ++gt)
            #pragma unroll
            for (int kt = 0; kt < 4; ++kt) {
                int n = gru * 384 + gt * 128 + ubase + utl * 16 + lr;
                Wf[utl * 3 + gt][kt] = *(const short8*)(whhbf + (long)n * 128 + kt * 32 + lo * 8);
            }
    // extra B tiles: waves 4-7 -> 2 beta tiles; wave 0 -> score tile (col0 = w_alpha)
    short8 Xf[2][4];
    #pragma unroll
    for (int tl = 0; tl < 2; ++tl)
        #pragma unroll
        for (int kt = 0; kt < 4; ++kt) {
            short8 z;
            #pragma unroll
            for (int jj = 0; jj < 8; ++jj) z[jj] = 0;
            Xf[tl][kt] = z;
        }
    if (w >= 4) {
        #pragma unroll
        for (int tl = 0; tl < 2; ++tl)
            #pragma unroll
            for (int kt = 0; kt < 4; ++kt) {
                int et = (w - 4) * 2 + tl;
                Xf[tl][kt] = *(const short8*)(wbetabf + (long)(et * 16 + lr) * 128 + kt * 32 + lo * 8);
            }
    } else if (w == 0 && lr == 0) {
        #pragma unroll
        for (int kt = 0; kt < 4; ++kt)
            #pragma unroll
            for (int jj = 0; jj < 8; ++jj)
                Xf[0][kt][jj] = (short)f2bf(w_alpha[kt * 32 + lo * 8 + jj]);
    }

    const float* bhh_g = gru ? bhh_b : bhh_a;
    const float bhn0 = bhh_g[256 + ubase + lr];
    const float bhn1 = bhh_g[256 + ubase + 16 + lr];
    float bbeta0 = 0.f, bbeta1 = 0.f;
    if (w >= 4) { bbeta0 = b_beta[(w - 4) * 32 + lr]; bbeta1 = b_beta[(w - 4) * 32 + 16 + lr]; }
    const float balpha0 = b_alpha[0];

    float h_old[2][4] = {{0, 0, 0, 0}, {0, 0, 0, 0}};
    float accv0[4] = {0, 0, 0, 0}, accv1[4] = {0, 0, 0, 0};
    f32x4 xacc_prev0 = {0, 0, 0, 0}, xacc_prev1 = {0, 0, 0, 0};
    float m0r[4] = {-1e30f, -1e30f, -1e30f, -1e30f};
    float lsum[4] = {0, 0, 0, 0};

    __syncthreads();

    const int iend = i + 2;
    for (int k = 0; k <= iend; ++k) {
        const int rb = k & 1, wb = rb ^ 1;
        const bool do_gru = (k <= i);
        const bool kx = (k >= 1 && k <= i + 1);
        const bool do_x = kx && (w >= 4 || w == 0);
        const bool do_accv = (k >= 2) && (w >= 4);
        const int j = i - k;
        const int jat = j + 2; // token for step k-2

        // ---- global prefetch for this iteration ----
        f32x4 giv[2][4];
        if (do_gru) {
            #pragma unroll
            for (int utl = 0; utl < 2; ++utl)
                #pragma unroll
                for (int r = 0; r < 4; ++r) {
                    int c = lo * 4 + r;
                    int tok = (q * 16 + c) * 64 + j;
                    giv[utl][r] = *(const f32x4*)(Gi3 + ((long)(tok * 2 + gru) * 128 + ubase + utl * 16 + lr) * 4);
                }
        }
        float ev_c[2][4];
        if (do_accv) {
            #pragma unroll
            for (int tl = 0; tl < 2; ++tl)
                #pragma unroll
                for (int r = 0; r < 4; ++r) {
                    int c = lo * 4 + r;
                    int tok = (q * 16 + c) * 64 + jat;
                    ev_c[tl][r] = emb[(long)tok * E + (w - 4) * 32 + tl * 16 + lr];
                }
        }

        // ---- LDS A-frags + MFMA ----
        f32x4 gh0, gh1, gh2, gh3, gh4, gh5;
        f32x4 xacc0 = {0, 0, 0, 0}, xacc1 = {0, 0, 0, 0};
        if (do_gru || do_x) {
            short8 Af[4];
            #pragma unroll
            for (int kt = 0; kt < 4; ++kt) {
                int sw = (kt * 32 + lo * 8) ^ ((lr & 7) * 8);
                Af[kt] = *(const short8*)(&Hbf[rb][gru][lr][sw]);
            }
            if (do_gru) {
                gh0 = (f32x4){0, 0, 0, 0}; gh1 = (f32x4){0, 0, 0, 0};
                gh2 = (f32x4){bhn0, bhn0, bhn0, bhn0};
                gh3 = (f32x4){0, 0, 0, 0}; gh4 = (f32x4){0, 0, 0, 0};
                gh5 = (f32x4){bhn1, bhn1, bhn1, bhn1};
                #pragma unroll
                for (int kt = 0; kt < 4; ++kt) {
                    gh0 = __builtin_amdgcn_mfma_f32_16x16x32_bf16(Af[kt], Wf[0][kt], gh0, 0, 0, 0);
                    gh1 = __builtin_amdgcn_mfma_f32_16x16x32_bf16(Af[kt], Wf[1][kt], gh1, 0, 0, 0);
                    gh2 = __builtin_amdgcn_mfma_f32_16x16x32_bf16(Af[kt], Wf[2][kt], gh2, 0, 0, 0);
                    gh3 = __builtin_amdgcn_mfma_f32_16x16x32_bf16(Af[kt], Wf[3][kt], gh3, 0, 0, 0);
                    gh4 = __builtin_amdgcn_mfma_f32_16x16x32_bf16(Af[kt], Wf[4][kt], gh4, 0, 0, 0);
                    gh5 = __builtin_amdgcn_mfma_f32_16x16x32_bf16(Af[kt], Wf[5][kt], gh5, 0, 0, 0);
                }
            }
            if (do_x) {
                #pragma unroll
                for (int kt = 0; kt < 4; ++kt)
                    xacc0 = __builtin_amdgcn_mfma_f32_16x16x32_bf16(Af[kt], Xf[0][kt], xacc0, 0, 0, 0);
                if (w >= 4) {
                    #pragma unroll
                    for (int kt = 0; kt < 4; ++kt)
                        xacc1 = __builtin_amdgcn_mfma_f32_16x16x32_bf16(Af[kt], Xf[1][kt], xacc1, 0, 0, 0);
                }
                // wave 0: online softmax scalars for step k-1
                if (w == 0 && lr == 0) {
                    #pragma unroll
                    for (int r = 0; r < 4; ++r) {
                        int c = lo * 4 + r;
                        float s = xacc0[r] + balpha0;
                        float mn = fmaxf(m0r[r], s);
                        float fac = __expf(m0r[r] - mn);
                        float p = __expf(s - mn);
                        lsum[r] = lsum[r] * fac + p;
                        m0r[r] = mn;
                        fac_s[k & 1][c] = fac;
                        p_s[k & 1][c] = p;
                    }
                }
            }
        }

        // ---- gates: H_k = GRU(H_{k-1}, x_j) ----
        if (do_gru) {
            #pragma unroll
            for (int utl = 0; utl < 2; ++utl) {
                #pragma unroll
                for (int r = 0; r < 4; ++r) {
                    f32x4 g = giv[utl][r];
                    float ghr = (utl ? gh3[r] : gh0[r]);
                    float ghz = (utl ? gh4[r] : gh1[r]);
                    float ghn = (utl ? gh5[r] : gh2[r]);
                    float rr = sigm(g[0] + ghr);
                    float zz = sigm(g[1] + ghz);
                    float nn = tanh_(g[2] + rr * ghn);
                    float h = nn + zz * (h_old[utl][r] - nn);
                    h_old[utl][r] = h;
                    int c = lo * 4 + r;
                    int u = ubase + utl * 16 + lr;
                    Hbf[wb][gru][c][u ^ ((c & 7) * 8)] = f2bf(h);
                }
            }
        }

        // ---- attention accumulation for step k-2 ----
        if (do_accv) {
            int sl = (k + 1) & 1;
            #pragma unroll
            for (int r = 0; r < 4; ++r) {
                int c = lo * 4 + r;
                float fac = fac_s[sl][c], p = p_s[sl][c];
                float beta0 = tanh_(xacc_prev0[r] + bbeta0);
                float beta1 = tanh_(xacc_prev1[r] + bbeta1);
                accv0[r] = accv0[r] * fac + p * beta0 * ev_c[0][r];
                accv1[r] = accv1[r] * fac + p * beta1 * ev_c[1][r];
            }
        }
        if (do_x && w >= 4) { xacc_prev0 = xacc0; xacc_prev1 = xacc1; }

        __syncthreads();
    }

    // ---- output ----
    if (w == 0 && lr == 0) {
        #pragma unroll
        for (int r = 0; r < 4; ++r) l_s[lo * 4 + r] = lsum[r];
    }
    if (w >= 4) {
        float wo0 = Wout[(w - 4) * 32 + lr], wo1 = Wout[(w - 4) * 32 + 16 + lr];
        #pragma unroll
        for (int r = 0; r < 4; ++r) {
            int c = lo * 4 + r;
            red_s[c][(w - 4) * 16 + lr] = accv0[r] * wo0 + accv1[r] * wo1;
        }
    }
    __syncthreads();
    if (w == 0) {
        int c = l >> 2, ch = l & 3;
        float s = 0.f;
        #pragma unroll
        for (int tt = 0; tt < 16; ++tt) s += red_s[c][ch * 16 + tt];
        s += __shfl_xor(s, 1);
        s += __shfl_xor(s, 2);
        if (ch == 0) {
            int b = q * 16 + c;
            float val = s / l_s[c] + b_out[0];
            if (i >= lengths[b]) val = b_out[0];
            out[b * TT + i] = val;
        }
    }
}

// ---------------- launch ----------------
extern "C" void kernel_launch(void* const* d_in, const int* in_sizes, int n_in,
                              void* d_out, int out_size, void* d_ws, size_t ws_size,
                              hipStream_t stream) {
    (void)in_sizes; (void)n_in; (void)out_size; (void)ws_size;
    const float* x       = (const float*)d_in[0];
    const float* t       = (const float*)d_in[1];
    const int*   len     = (const int*)d_in[2];
    const float* Wemb    = (const float*)d_in[3];
    const float* Wih_a   = (const float*)d_in[4];
    const float* Whh_a   = (const float*)d_in[5];
    const float* bih_a   = (const float*)d_in[6];
    const float* bhh_a   = (const float*)d_in[7];
    const float* Wih_b   = (const float*)d_in[8];
    const float* Whh_b   = (const float*)d_in[9];
    const float* bih_b   = (const float*)d_in[10];
    const float* bhh_b   = (const float*)d_in[11];
    const float* w_alpha = (const float*)d_in[12];
    const float* b_alpha = (const float*)d_in[13];
    const float* W_beta  = (const float*)d_in[14];
    const float* b_beta  = (const float*)d_in[15];
    const float* W_out   = (const float*)d_in[16];
    const float* b_out   = (const float*)d_in[17];

    char* ws = (char*)d_ws;
    float*          emb     = (float*)(ws + 0);                 // 1,048,576
    unsigned short* embbf   = (unsigned short*)(ws + 1048576);  //   524,288
    float*          Gi3     = (float*)(ws + 1572864);           // 8,388,608 (tok x gru x u x 4)
    unsigned short* wembbf  = (unsigned short*)(ws + 9961472);  // 1,253,376
    unsigned short* wihbf   = (unsigned short*)(ws + 11214848); //   196,608
    unsigned short* whhbf   = (unsigned short*)(ws + 11411456); //   196,608
    unsigned short* wbetabf = (unsigned short*)(ws + 11608064); //    32,768
    float*          col128  = (float*)(ws + 11640832);          //     3,072

    const int jobs = 128 * 612 + 768 * 16 + 768 * 16 + 128 * 16 + 96; // 105,056
    const int prep_blocks = (jobs + 255) / 256;

    prep_kernel<<<prep_blocks, 256, 0, stream>>>(Wemb, Wih_a, Wih_b, Whh_a, Whh_b, W_beta,
                                                 wembbf, wihbf, whhbf, wbetabf, col128);
    emb_gemm<<<128, 256, 0, stream>>>(x, wembbf, emb, embbf);
    gi_gemm<<<64, 256, 0, stream>>>(embbf, wihbf, t, bih_a, bih_b, bhh_a, bhh_b, col128, Gi3);
    retain_rec<<<128, 512, 0, stream>>>(whhbf, wbetabf, Gi3, emb, bhh_a, bhh_b,
                                        w_alpha, b_alpha, b_beta, W_out, b_out, len, (float*)d_out);
}

// Round 4
// 303.549 us; speedup vs baseline: 1.0312x; 1.0312x over previous
//
#include <hip/hip_runtime.h>
#include <hip/hip_bf16.h>

#define DEVI __device__ __forceinline__

typedef __attribute__((ext_vector_type(8))) short short8;
typedef __attribute__((ext_vector_type(4))) float f32x4;

static constexpr int TT = 64, KIN = 4894;
static constexpr int E = 128;
static constexpr float L2E = 1.4426950408889634f;

DEVI unsigned short f2bf(float f) {
    union { float f; unsigned u; } v; v.f = f;
    unsigned r = v.u + 0x7fffu + ((v.u >> 16) & 1u);
    return (unsigned short)(r >> 16);
}
// args pre-scaled by log2(e): exp(x) == exp2(x*L2E)
DEVI float sigm2(float x) { return __builtin_amdgcn_rcpf(1.f + __builtin_amdgcn_exp2f(-x)); }
DEVI float tanh2(float x) { return 1.f - 2.f * __builtin_amdgcn_rcpf(__builtin_amdgcn_exp2f(x + x) + 1.f); }

// ---------------- emb = x @ Wemb^T, f32 inputs converted in-register ----------------
__global__ __launch_bounds__(512) void emb_gemm(const float* __restrict__ x,
                                                const float* __restrict__ Wemb,
                                                float* __restrict__ emb,
                                                unsigned short* __restrict__ embbf) {
    const int m0 = blockIdx.x * 16;
    const int w = threadIdx.x >> 6, l = threadIdx.x & 63, lr = l & 15, lo = l >> 4;
    const int n = w * 16 + lr;
    const float* xrow = x + (long)(m0 + lr) * KIN;
    const float* wrow = Wemb + (long)n * KIN;
    f32x4 acc = {0, 0, 0, 0};
    #pragma unroll 2
    for (int kt = 0; kt < 152; ++kt) {
        int k = kt * 32 + lo * 8;
        short8 a, b;
        #pragma unroll
        for (int h = 0; h < 4; ++h) {
            float2 xa = *(const float2*)(xrow + k + 2 * h);
            float2 wb = *(const float2*)(wrow + k + 2 * h);
            a[2 * h] = (short)f2bf(xa.x); a[2 * h + 1] = (short)f2bf(xa.y);
            b[2 * h] = (short)f2bf(wb.x); b[2 * h + 1] = (short)f2bf(wb.y);
        }
        acc = __builtin_amdgcn_mfma_f32_16x16x32_bf16(a, b, acc, 0, 0, 0);
    }
    { // tail k-tile: guard columns >= 4894
        int k = 4864 + lo * 8;
        short8 a, b;
        #pragma unroll
        for (int jj = 0; jj < 8; ++jj) {
            int c = k + jj;
            a[jj] = (c < KIN) ? (short)f2bf(xrow[c]) : (short)0;
            b[jj] = (c < KIN) ? (short)f2bf(wrow[c]) : (short)0;
        }
        acc = __builtin_amdgcn_mfma_f32_16x16x32_bf16(a, b, acc, 0, 0, 0);
    }
    #pragma unroll
    for (int r = 0; r < 4; ++r) {
        int m = m0 + lo * 4 + r;
        emb[(long)m * E + n] = acc[r];
        embbf[(long)m * E + n] = f2bf(acc[r]);
    }
}

// ---------------- Gi3 = log2e * (temb @ Wih^T + bih + bhh(r,z)), [tok][gru][u][r,z,n,pad] ----------------
__global__ __launch_bounds__(256) void gi_gemm(const unsigned short* __restrict__ embbf,
                                               const float* __restrict__ Wih_a, const float* __restrict__ Wih_b,
                                               const float* __restrict__ t,
                                               const float* __restrict__ bih_a, const float* __restrict__ bih_b,
                                               const float* __restrict__ bhh_a, const float* __restrict__ bhh_b,
                                               float* __restrict__ Gi3) {
    const int m0 = blockIdx.x * 32;
    const int w = threadIdx.x >> 6, l = threadIdx.x & 63, lr = l & 15, lo = l >> 4;
    f32x4 acc[2][12];
    #pragma unroll
    for (int mt = 0; mt < 2; ++mt)
        #pragma unroll
        for (int nl = 0; nl < 12; ++nl) acc[mt][nl] = (f32x4){0, 0, 0, 0};
    #pragma unroll
    for (int kt = 0; kt < 4; ++kt) {
        int k = kt * 32 + lo * 8;
        short8 a0 = *(const short8*)(embbf + (long)(m0 + lr) * E + k);
        short8 a1 = *(const short8*)(embbf + (long)(m0 + 16 + lr) * E + k);
        #pragma unroll
        for (int nl = 0; nl < 12; ++nl) {
            int n = (w * 12 + nl) * 16 + lr;
            const float* src = ((n < 384) ? (Wih_a + (long)n * 129) : (Wih_b + (long)(n - 384) * 129)) + k;
            short8 bf;
            #pragma unroll
            for (int jj = 0; jj < 8; ++jj) bf[jj] = (short)f2bf(src[jj] * L2E);
            acc[0][nl] = __builtin_amdgcn_mfma_f32_16x16x32_bf16(a0, bf, acc[0][nl], 0, 0, 0);
            acc[1][nl] = __builtin_amdgcn_mfma_f32_16x16x32_bf16(a1, bf, acc[1][nl], 0, 0, 0);
        }
    }
    #pragma unroll
    for (int mt = 0; mt < 2; ++mt)
        #pragma unroll
        for (int nl = 0; nl < 12; ++nl) {
            int n = (w * 12 + nl) * 16 + lr;
            int gru = (n >= 384) ? 1 : 0;
            int nn = n - gru * 384;
            int gt = nn >> 7, u = nn & 127;
            float bias = (gru ? bih_b[nn] : bih_a[nn]);
            if (gt < 2) bias += (gru ? bhh_b[nn] : bhh_a[nn]);
            float cw = (n < 384) ? Wih_a[(long)n * 129 + 128] : Wih_b[(long)(n - 384) * 129 + 128];
            #pragma unroll
            for (int r = 0; r < 4; ++r) {
                int tok = m0 + mt * 16 + lo * 4 + r;
                Gi3[((long)(tok * 2 + gru) * 128 + u) * 4 + gt] = acc[mt][nl][r] + (bias + t[tok] * cw) * L2E;
            }
        }
}

// ---------------- recurrence + (no-max) online softmax attention, 1 barrier/step ----------------
// 128 blocks = (i 0..63) x (q 0..1); 16 chains/block; 8 waves; gru = w>>2.
// Iter k: gates H_{k-1}->H_k (+ score partials of H_k via VALU+shfl),
//         beta-preact MFMA of H_{k-1} (all 8 waves, 1 e-tile each),
//         wave0 finishes p of step k-1, accv accumulates step k-2.
// Working set kept < 256 unified regs (2 waves/SIMD): Wf 96 + Xf 16 in AGPR-eligible frags.
__global__ __launch_bounds__(512) __attribute__((amdgpu_waves_per_eu(2, 2)))
void retain_rec(const float* __restrict__ Whh_a, const float* __restrict__ Whh_b,
                const float* __restrict__ Wbeta,
                const float* __restrict__ Gi3, const float* __restrict__ emb,
                const float* __restrict__ bhh_a, const float* __restrict__ bhh_b,
                const float* __restrict__ w_alpha, const float* __restrict__ b_alpha,
                const float* __restrict__ b_beta, const float* __restrict__ Wout,
                const float* __restrict__ b_out, const int* __restrict__ lengths,
                float* __restrict__ out) {
    const int tid = threadIdx.x;
    const int w = tid >> 6, l = tid & 63, lr = l & 15, lo = l >> 4;
    const int i = blockIdx.x >> 1, q = blockIdx.x & 1;
    const int gru = w >> 2, ubase = (w & 3) * 32;

    __shared__ __align__(16) unsigned short Hbf[2][2][16][128]; // [buf][gru][c][u ^ ((c&7)*8)]
    __shared__ float s_red[2][4][16];
    __shared__ float p_s[2][16];
    __shared__ float l_s[16];
    __shared__ float red_s[16][132];

    for (int idx = tid; idx < 2 * 16 * 128; idx += 512) (&Hbf[0][0][0][0])[idx] = 0; // H_{-1}=0

    // Whh B-fragments, f32 -> bf16 * log2e in-register (one-time)
    const float* WhhG = gru ? Whh_b : Whh_a;
    short8 Wf[6][4];
    #pragma unroll
    for (int utl = 0; utl < 2; ++utl)
        #pragma unroll
        for (int gt = 0; gt < 3; ++gt)
            #pragma unroll
            for (int kt = 0; kt < 4; ++kt) {
                const float* src = WhhG + (long)(gt * 128 + ubase + utl * 16 + lr) * 128 + kt * 32 + lo * 8;
                f32x4 v0 = *(const f32x4*)src;
                f32x4 v1 = *(const f32x4*)(src + 4);
                short8 f;
                #pragma unroll
                for (int jj = 0; jj < 4; ++jj) { f[jj] = (short)f2bf(v0[jj] * L2E); f[4 + jj] = (short)f2bf(v1[jj] * L2E); }
                Wf[utl * 3 + gt][kt] = f;
            }
    short8 Xf[4]; // beta e-tile: e = w*16 + lr
    #pragma unroll
    for (int kt = 0; kt < 4; ++kt) {
        const float* src = Wbeta + (long)(w * 16 + lr) * 128 + kt * 32 + lo * 8;
        f32x4 v0 = *(const f32x4*)src;
        f32x4 v1 = *(const f32x4*)(src + 4);
        short8 f;
        #pragma unroll
        for (int jj = 0; jj < 4; ++jj) { f[jj] = (short)f2bf(v0[jj] * L2E); f[4 + jj] = (short)f2bf(v1[jj] * L2E); }
        Xf[kt] = f;
    }

    const float* bhhG = gru ? bhh_b : bhh_a;
    const float bhn0 = bhhG[256 + ubase + lr] * L2E;
    const float bhn1 = bhhG[256 + ubase + 16 + lr] * L2E;
    const float bbet = b_beta[w * 16 + lr] * L2E;
    const float wa0 = w_alpha[ubase + lr] * L2E;
    const float wa1 = w_alpha[ubase + 16 + lr] * L2E;
    const float balL = b_alpha[0] * L2E;

    float h_old[2][4] = {{0, 0, 0, 0}, {0, 0, 0, 0}};
    float accv[4] = {0, 0, 0, 0};
    f32x4 xacc_prev = {0, 0, 0, 0};
    float lsum = 0.f;

    __syncthreads();

    const int iend = i + 2;
    for (int k = 0; k <= iend; ++k) {
        const int rb = k & 1, wb = rb ^ 1;
        const bool do_gru = (k <= i);
        const bool kx = (k >= 1) && (k <= i + 1);
        const bool do_acc = (k >= 2);
        const int j = i - k;
        const int jc = (j < 0) ? 0 : j;
        int jat = j + 2; if (jat > 63) jat = 63;

        // gate-input + emb prefetch (unconditional, clamped indices)
        f32x4 giv[2][4];
        #pragma unroll
        for (int utl = 0; utl < 2; ++utl)
            #pragma unroll
            for (int r = 0; r < 4; ++r) {
                int tok = (q * 16 + lo * 4 + r) * 64 + jc;
                giv[utl][r] = *(const f32x4*)(Gi3 + ((long)(tok * 2 + gru) * 128 + ubase + utl * 16 + lr) * 4);
            }
        float ev[4];
        #pragma unroll
        for (int r = 0; r < 4; ++r) {
            int tok = (q * 16 + lo * 4 + r) * 64 + jat;
            ev[r] = emb[(long)tok * E + w * 16 + lr];
        }

        // A-fragments from swizzled LDS
        short8 Af[4], Afb[4];
        #pragma unroll
        for (int kt = 0; kt < 4; ++kt) {
            int sw = (kt * 32 + lo * 8) ^ ((lr & 7) * 8);
            Af[kt] = *(const short8*)(&Hbf[rb][gru][lr][sw]);
        }
        if (gru == 0) {
            #pragma unroll
            for (int kt = 0; kt < 4; ++kt) {
                int sw = (kt * 32 + lo * 8) ^ ((lr & 7) * 8);
                Afb[kt] = *(const short8*)(&Hbf[rb][1][lr][sw]);
            }
        } else {
            #pragma unroll
            for (int kt = 0; kt < 4; ++kt) Afb[kt] = Af[kt];
        }

        // wave0: finish softmax p for step k-1 (s_red written at iter k-1, slot wb)
        if (w == 0 && l < 16 && kx) {
            float s = s_red[wb][0][l] + s_red[wb][1][l] + s_red[wb][2][l] + s_red[wb][3][l] + balL;
            float p = __builtin_amdgcn_exp2f(s);
            p_s[wb][l] = p;
            lsum += p;
        }

        // MFMA: 6 gate tiles + 1 beta tile
        f32x4 gh0 = {0, 0, 0, 0}, gh1 = {0, 0, 0, 0}, gh2 = {bhn0, bhn0, bhn0, bhn0};
        f32x4 gh3 = {0, 0, 0, 0}, gh4 = {0, 0, 0, 0}, gh5 = {bhn1, bhn1, bhn1, bhn1};
        f32x4 xacc = {0, 0, 0, 0};
        #pragma unroll
        for (int kt = 0; kt < 4; ++kt) {
            gh0 = __builtin_amdgcn_mfma_f32_16x16x32_bf16(Af[kt], Wf[0][kt], gh0, 0, 0, 0);
            gh1 = __builtin_amdgcn_mfma_f32_16x16x32_bf16(Af[kt], Wf[1][kt], gh1, 0, 0, 0);
            gh2 = __builtin_amdgcn_mfma_f32_16x16x32_bf16(Af[kt], Wf[2][kt], gh2, 0, 0, 0);
            gh3 = __builtin_amdgcn_mfma_f32_16x16x32_bf16(Af[kt], Wf[3][kt], gh3, 0, 0, 0);
            gh4 = __builtin_amdgcn_mfma_f32_16x16x32_bf16(Af[kt], Wf[4][kt], gh4, 0, 0, 0);
            gh5 = __builtin_amdgcn_mfma_f32_16x16x32_bf16(Af[kt], Wf[5][kt], gh5, 0, 0, 0);
            xacc = __builtin_amdgcn_mfma_f32_16x16x32_bf16(Afb[kt], Xf[kt], xacc, 0, 0, 0);
        }

        // context accumulation for step k-2 (no rescale: no-max softmax)
        if (do_acc) {
            #pragma unroll
            for (int r = 0; r < 4; ++r) {
                float p = p_s[rb][lo * 4 + r];
                float beta = tanh2(xacc_prev[r] + bbet);
                accv[r] += p * beta * ev[r];
            }
        }

        // gates: H_k = GRU(H_{k-1}, x_j); score partials from f32 h
        if (do_gru) {
            float sp[4] = {0.f, 0.f, 0.f, 0.f};
            #pragma unroll
            for (int utl = 0; utl < 2; ++utl) {
                #pragma unroll
                for (int r = 0; r < 4; ++r) {
                    f32x4 g = giv[utl][r];
                    float ghr = utl ? gh3[r] : gh0[r];
                    float ghz = utl ? gh4[r] : gh1[r];
                    float ghn = utl ? gh5[r] : gh2[r];
                    float rr = sigm2(g[0] + ghr);
                    float zz = sigm2(g[1] + ghz);
                    float nn = tanh2(g[2] + rr * ghn);
                    float h = nn + zz * (h_old[utl][r] - nn);
                    h_old[utl][r] = h;
                    int c = lo * 4 + r;
                    Hbf[wb][gru][c][(ubase + utl * 16 + lr) ^ ((c & 7) * 8)] = f2bf(h);
                    sp[r] += h * (utl ? wa1 : wa0);
                }
            }
            if (gru == 0) {
                #pragma unroll
                for (int r = 0; r < 4; ++r) {
                    sp[r] += __shfl_xor(sp[r], 1);
                    sp[r] += __shfl_xor(sp[r], 2);
                    sp[r] += __shfl_xor(sp[r], 4);
                    sp[r] += __shfl_xor(sp[r], 8);
                }
                if (lr == 0) {
                    #pragma unroll
                    for (int r = 0; r < 4; ++r) s_red[rb][w][lo * 4 + r] = sp[r];
                }
            }
        }

        if (kx) xacc_prev = xacc; // beta-preact of step k-1, consumed at iter k+1

        __syncthreads();
    }

    // ---- output ----
    if (w == 0 && l < 16) l_s[l] = lsum;
    {
        float wo = Wout[w * 16 + lr];
        #pragma unroll
        for (int r = 0; r < 4; ++r)
            red_s[lo * 4 + r][w * 16 + lr] = accv[r] * wo;
    }
    __syncthreads();
    if (w == 0) {
        int c = l >> 2, ch = l & 3;
        float s = 0.f;
        #pragma unroll
        for (int tt2 = 0; tt2 < 32; ++tt2) s += red_s[c][ch * 32 + tt2];
        s += __shfl_xor(s, 1);
        s += __shfl_xor(s, 2);
        if (ch == 0) {
            int b = q * 16 + c;
            float val = s / l_s[c] + b_out[0];
            if (i >= lengths[b]) val = b_out[0];
            out[b * TT + i] = val;
        }
    }
}

// ---------------- launch ----------------
extern "C" void kernel_launch(void* const* d_in, const int* in_sizes, int n_in,
                              void* d_out, int out_size, void* d_ws, size_t ws_size,
                              hipStream_t stream) {
    (void)in_sizes; (void)n_in; (void)out_size; (void)ws_size;
    const float* x       = (const float*)d_in[0];
    const float* t       = (const float*)d_in[1];
    const int*   len     = (const int*)d_in[2];
    const float* Wemb    = (const float*)d_in[3];
    const float* Wih_a   = (const float*)d_in[4];
    const float* Whh_a   = (const float*)d_in[5];
    const float* bih_a   = (const float*)d_in[6];
    const float* bhh_a   = (const float*)d_in[7];
    const float* Wih_b   = (const float*)d_in[8];
    const float* Whh_b   = (const float*)d_in[9];
    const float* bih_b   = (const float*)d_in[10];
    const float* bhh_b   = (const float*)d_in[11];
    const float* w_alpha = (const float*)d_in[12];
    const float* b_alpha = (const float*)d_in[13];
    const float* W_beta  = (const float*)d_in[14];
    const float* b_beta  = (const float*)d_in[15];
    const float* W_out   = (const float*)d_in[16];
    const float* b_out   = (const float*)d_in[17];

    char* ws = (char*)d_ws;
    float*          emb   = (float*)(ws + 0);                // 2048*128*4 = 1,048,576
    unsigned short* embbf = (unsigned short*)(ws + 1048576); // 2048*128*2 =   524,288
    float*          Gi3   = (float*)(ws + 1572864);          // 2048*2*128*4*4 = 8,388,608

    emb_gemm<<<128, 512, 0, stream>>>(x, Wemb, emb, embbf);
    gi_gemm<<<64, 256, 0, stream>>>(embbf, Wih_a, Wih_b, t, bih_a, bih_b, bhh_a, bhh_b, Gi3);
    retain_rec<<<128, 512, 0, stream>>>(Whh_a, Whh_b, W_beta, Gi3, emb, bhh_a, bhh_b,
                                        w_alpha, b_alpha, b_beta, W_out, b_out, len, (float*)d_out);
}

// Round 5
// 283.758 us; speedup vs baseline: 1.1031x; 1.0697x over previous
//
#include <hip/hip_runtime.h>
#include <hip/hip_bf16.h>

#define DEVI __device__ __forceinline__

typedef __attribute__((ext_vector_type(8))) short short8;
typedef __attribute__((ext_vector_type(8))) unsigned short ushort8;
typedef __attribute__((ext_vector_type(4))) float f32x4;

static constexpr int TT = 64, KIN = 4894, KINP = 4896, E = 128;
static constexpr float L2E = 1.4426950408889634f;

DEVI unsigned short f2bf(float f) {
    union { float f; unsigned u; } v; v.f = f;
    unsigned r = v.u + 0x7fffu + ((v.u >> 16) & 1u);
    return (unsigned short)(r >> 16);
}
// args pre-scaled by log2(e): exp(x) == exp2(x*L2E)
DEVI float sigm2(float x) { return __builtin_amdgcn_rcpf(1.f + __builtin_amdgcn_exp2f(-x)); }
DEVI float tanh2(float x) { return 1.f - 2.f * __builtin_amdgcn_rcpf(__builtin_amdgcn_exp2f(x + x) + 1.f); }

// ---------------- prep: weight casts (Wih/Whh/Wbeta pre-scaled by log2e) ----------------
__global__ void prep_kernel(const float* __restrict__ Wemb,
                            const float* __restrict__ Wih_a, const float* __restrict__ Wih_b,
                            const float* __restrict__ Whh_a, const float* __restrict__ Whh_b,
                            const float* __restrict__ Wbeta,
                            unsigned short* __restrict__ wembbf, unsigned short* __restrict__ wihbf,
                            unsigned short* __restrict__ whhbf, unsigned short* __restrict__ wbetabf) {
    int job = blockIdx.x * blockDim.x + threadIdx.x;
    const int JWE = 128 * 612, JWIH = 768 * 16, JWHH = 768 * 16, JWB = 128 * 16;
    if (job < JWE) {
        int row = job / 612, c8 = (job % 612) * 8;
        ushort8 v;
        #pragma unroll
        for (int jj = 0; jj < 8; ++jj) { int c = c8 + jj; v[jj] = (c < KIN) ? f2bf(Wemb[(long)row * KIN + c]) : (unsigned short)0; }
        *(ushort8*)(wembbf + (long)row * KINP + c8) = v;
        return;
    }
    job -= JWE;
    if (job < JWIH) {
        int g = job / 16, c8 = (job % 16) * 8;
        const float* src = (g < 384) ? (Wih_a + (long)g * 129) : (Wih_b + (long)(g - 384) * 129);
        ushort8 v;
        #pragma unroll
        for (int jj = 0; jj < 8; ++jj) v[jj] = f2bf(src[c8 + jj] * L2E);
        *(ushort8*)(wihbf + (long)g * 128 + c8) = v;
        return;
    }
    job -= JWIH;
    if (job < JWHH) {
        int g = job / 16, c8 = (job % 16) * 8;
        const float* src = (g < 384) ? (Whh_a + (long)g * 128) : (Whh_b + (long)(g - 384) * 128);
        ushort8 v;
        #pragma unroll
        for (int jj = 0; jj < 8; ++jj) v[jj] = f2bf(src[c8 + jj] * L2E);
        *(ushort8*)(whhbf + (long)g * 128 + c8) = v;
        return;
    }
    job -= JWHH;
    if (job < JWB) {
        int e = job / 16, c8 = (job % 16) * 8;
        ushort8 v;
        #pragma unroll
        for (int jj = 0; jj < 8; ++jj) v[jj] = f2bf(Wbeta[(long)e * 128 + c8 + jj] * L2E);
        *(ushort8*)(wbetabf + (long)e * 128 + c8) = v;
    }
}

// ---------------- emb = x @ Wemb^T  (32 blocks x M=64: Wemb L3 refetch 40MB not 320MB) ----------------
__global__ __launch_bounds__(512) void emb_gemm(const float* __restrict__ x,
                                                const unsigned short* __restrict__ wembbf,
                                                float* __restrict__ emb, unsigned short* __restrict__ embbf) {
    const int w = threadIdx.x >> 6, l = threadIdx.x & 63, lr = l & 15, lo = l >> 4;
    const int mt = w >> 1, nh = w & 1;           // wave = (m-tile, n-half)
    const int mrow = blockIdx.x * 64 + mt * 16 + lr;
    const float* xrow = x + (long)mrow * KIN;
    f32x4 acc[4];
    #pragma unroll
    for (int nt = 0; nt < 4; ++nt) acc[nt] = (f32x4){0, 0, 0, 0};
    #pragma unroll 2
    for (int kt = 0; kt < 152; ++kt) {
        int k = kt * 32 + lo * 8;
        float2 x0 = *(const float2*)(xrow + k);
        float2 x1 = *(const float2*)(xrow + k + 2);
        float2 x2 = *(const float2*)(xrow + k + 4);
        float2 x3 = *(const float2*)(xrow + k + 6);
        short8 a;
        a[0] = (short)f2bf(x0.x); a[1] = (short)f2bf(x0.y);
        a[2] = (short)f2bf(x1.x); a[3] = (short)f2bf(x1.y);
        a[4] = (short)f2bf(x2.x); a[5] = (short)f2bf(x2.y);
        a[6] = (short)f2bf(x3.x); a[7] = (short)f2bf(x3.y);
        #pragma unroll
        for (int nt = 0; nt < 4; ++nt) {
            int n = nh * 64 + nt * 16 + lr;
            short8 b = *(const short8*)(wembbf + (long)n * KINP + k);
            acc[nt] = __builtin_amdgcn_mfma_f32_16x16x32_bf16(a, b, acc[nt], 0, 0, 0);
        }
    }
    { // tail k-tile: guard columns >= 4894 (wembbf already zero-padded)
        int k = 4864 + lo * 8;
        short8 a;
        #pragma unroll
        for (int jj = 0; jj < 8; ++jj) { int c = k + jj; a[jj] = (c < KIN) ? (short)f2bf(xrow[c]) : (short)0; }
        #pragma unroll
        for (int nt = 0; nt < 4; ++nt) {
            int n = nh * 64 + nt * 16 + lr;
            short8 b = *(const short8*)(wembbf + (long)n * KINP + k);
            acc[nt] = __builtin_amdgcn_mfma_f32_16x16x32_bf16(a, b, acc[nt], 0, 0, 0);
        }
    }
    #pragma unroll
    for (int nt = 0; nt < 4; ++nt) {
        int n = nh * 64 + nt * 16 + lr;
        #pragma unroll
        for (int r = 0; r < 4; ++r) {
            int m = blockIdx.x * 64 + mt * 16 + lo * 4 + r;
            emb[(long)m * E + n] = acc[nt][r];
            embbf[(long)m * E + n] = f2bf(acc[nt][r]);
        }
    }
}

// ---------------- Gi3 = log2e*(temb @ Wih^T + bih + bhh(r,z)), [tok][gru][u][r,z,n,pad] ----------------
__global__ __launch_bounds__(256) void gi_gemm(const unsigned short* __restrict__ embbf,
                                               const unsigned short* __restrict__ wihbf,
                                               const float* __restrict__ Wih_a, const float* __restrict__ Wih_b,
                                               const float* __restrict__ t,
                                               const float* __restrict__ bih_a, const float* __restrict__ bih_b,
                                               const float* __restrict__ bhh_a, const float* __restrict__ bhh_b,
                                               float* __restrict__ Gi3) {
    const int m0 = blockIdx.x * 32;
    const int w = threadIdx.x >> 6, l = threadIdx.x & 63, lr = l & 15, lo = l >> 4;
    f32x4 acc[2][12];
    #pragma unroll
    for (int mt = 0; mt < 2; ++mt)
        #pragma unroll
        for (int nl = 0; nl < 12; ++nl) acc[mt][nl] = (f32x4){0, 0, 0, 0};
    #pragma unroll
    for (int kt = 0; kt < 4; ++kt) {
        int k = kt * 32 + lo * 8;
        short8 a0 = *(const short8*)(embbf + (long)(m0 + lr) * E + k);
        short8 a1 = *(const short8*)(embbf + (long)(m0 + 16 + lr) * E + k);
        #pragma unroll
        for (int nl = 0; nl < 12; ++nl) {
            int n = (w * 12 + nl) * 16 + lr;
            short8 bf = *(const short8*)(wihbf + (long)n * 128 + k);
            acc[0][nl] = __builtin_amdgcn_mfma_f32_16x16x32_bf16(a0, bf, acc[0][nl], 0, 0, 0);
            acc[1][nl] = __builtin_amdgcn_mfma_f32_16x16x32_bf16(a1, bf, acc[1][nl], 0, 0, 0);
        }
    }
    #pragma unroll
    for (int mt = 0; mt < 2; ++mt)
        #pragma unroll
        for (int nl = 0; nl < 12; ++nl) {
            int n = (w * 12 + nl) * 16 + lr;
            int gru = (n >= 384) ? 1 : 0;
            int nn = n - gru * 384;
            int gt = nn >> 7, u = nn & 127;
            float bias = (gru ? bih_b[nn] : bih_a[nn]);
            if (gt < 2) bias += (gru ? bhh_b[nn] : bhh_a[nn]);
            float cw = (n < 384) ? Wih_a[(long)n * 129 + 128] : Wih_b[(long)(n - 384) * 129 + 128];
            #pragma unroll
            for (int r = 0; r < 4; ++r) {
                int tok = m0 + mt * 16 + lo * 4 + r;
                Gi3[((long)(tok * 2 + gru) * 128 + u) * 4 + gt] = acc[mt][nl][r] + (bias + t[tok] * cw) * L2E;
            }
        }
}

// ---------------- recurrence, ONE GRU per block ----------------
// 256 blocks = (i 0..63) x (q 0..1) x (g 0..1). 512 thr, 8 waves; wave w owns u-slice w*16+lr.
// Alpha blocks (g=0): GRU-a chains -> unnormalized softmax p[b,i,k] to global.
// Beta blocks (g=1): GRU-b chains -> d[b,i,k] = (tanh(Hb Wb^T + b) . emb_j . Wout) to global.
// Iter n: gates step n (H_{n-1}->H_n); alpha score partial of H_n / beta MFMA of H_{n-1};
// wave0 finishes previous partial sums from LDS (parity-lagged), 1 barrier/iter.
// Per-wave regs ~150 (Wf 48 + Xf 16 + Af 16 + giv 16 + gh 12 + misc) -> no spill.
__global__ __launch_bounds__(512) __attribute__((amdgpu_waves_per_eu(2, 2)))
void retain_rec(const unsigned short* __restrict__ whhbf, const unsigned short* __restrict__ wbetabf,
                const float* __restrict__ Gi3, const float* __restrict__ emb,
                const float* __restrict__ bhh_a, const float* __restrict__ bhh_b,
                const float* __restrict__ w_alpha, const float* __restrict__ b_alpha,
                const float* __restrict__ b_beta, const float* __restrict__ Wout,
                float* __restrict__ p_g, float* __restrict__ d_g) {
    const int tid = threadIdx.x;
    const int w = tid >> 6, l = tid & 63, lr = l & 15, lo = l >> 4;
    const int i = blockIdx.x >> 2, q = (blockIdx.x >> 1) & 1, g = blockIdx.x & 1;
    const int u = w * 16 + lr;

    __shared__ __align__(16) unsigned short Hbf[2][16][128]; // [buf][c][u ^ ((c&7)*8)]
    __shared__ float red[2][8][16];                          // parity-lagged partial sums

    for (int idx = tid; idx < 2 * 16 * 128; idx += 512) (&Hbf[0][0][0])[idx] = 0; // H_{-1}=0

    // Whh B-fragments for this GRU (pre-scaled by log2e in prep)
    short8 Wf[3][4];
    #pragma unroll
    for (int gt = 0; gt < 3; ++gt)
        #pragma unroll
        for (int kt = 0; kt < 4; ++kt)
            Wf[gt][kt] = *(const short8*)(whhbf + (long)(g * 384 + gt * 128 + u) * 128 + kt * 32 + lo * 8);

    short8 Xf[4];
    float bbetL = 0.f, wo = 0.f;
    if (g) {
        #pragma unroll
        for (int kt = 0; kt < 4; ++kt)
            Xf[kt] = *(const short8*)(wbetabf + (long)u * 128 + kt * 32 + lo * 8);
        bbetL = b_beta[u] * L2E;
        wo = Wout[u];
    } else {
        #pragma unroll
        for (int kt = 0; kt < 4; ++kt) {
            short8 z;
            #pragma unroll
            for (int jj = 0; jj < 8; ++jj) z[jj] = 0;
            Xf[kt] = z;
        }
    }

    const float bhnL = (g ? bhh_b : bhh_a)[256 + u] * L2E;
    const float waL = g ? 0.f : w_alpha[u] * L2E;
    const float balL = b_alpha[0] * L2E;

    float h_old[4] = {0, 0, 0, 0};
    __syncthreads();

    for (int n = 0; n <= i + 2; ++n) {
        const int rb = n & 1, wb = rb ^ 1;
        const bool do_gate = (n <= i);
        const bool do_post = (n >= 1) && (n <= i + 1); // step n-1 finish (alpha p / beta MFMA)

        // ---- wave0: finish previous partial sums -> global ----
        if (w == 0 && l < 16) {
            const long row = (long)(q * 16 + l) * 64 + i;
            if (!g) {
                if (do_post) { // p for step n-1 (score partials of H_{n-1} written at iter n-1)
                    float s = balL;
                    #pragma unroll
                    for (int ww = 0; ww < 8; ++ww) s += red[wb][ww][l];
                    p_g[row * 64 + (n - 1)] = __builtin_amdgcn_exp2f(s);
                }
            } else {
                if (n >= 2) { // d for step n-2 (beta partials written at iter n-1)
                    float d = 0.f;
                    #pragma unroll
                    for (int ww = 0; ww < 8; ++ww) d += red[wb][ww][l];
                    d_g[row * 64 + (n - 2)] = d;
                }
            }
        }

        // ---- prefetch ----
        f32x4 giv[4];
        if (do_gate) {
            const int j = i - n;
            #pragma unroll
            for (int r = 0; r < 4; ++r) {
                int tok = (q * 16 + lo * 4 + r) * 64 + j;
                giv[r] = *(const f32x4*)(Gi3 + ((long)(tok * 2 + g) * 128 + u) * 4);
            }
        }
        float ev[4];
        if (g && do_post) {
            const int j2 = i - n + 1;
            #pragma unroll
            for (int r = 0; r < 4; ++r) {
                int tok = (q * 16 + lo * 4 + r) * 64 + j2;
                ev[r] = emb[(long)tok * E + u];
            }
        }

        // ---- A-fragments from swizzled LDS (H_{n-1}) ----
        short8 Af[4];
        if (do_gate || (g && do_post)) {
            #pragma unroll
            for (int kt = 0; kt < 4; ++kt) {
                int sw = (kt * 32 + lo * 8) ^ ((lr & 7) * 8);
                Af[kt] = *(const short8*)(&Hbf[rb][lr][sw]);
            }
        }

        // ---- MFMA ----
        f32x4 gh0 = {0, 0, 0, 0}, gh1 = {0, 0, 0, 0}, gh2 = {bhnL, bhnL, bhnL, bhnL};
        f32x4 xacc = {0, 0, 0, 0};
        if (do_gate) {
            #pragma unroll
            for (int kt = 0; kt < 4; ++kt) {
                gh0 = __builtin_amdgcn_mfma_f32_16x16x32_bf16(Af[kt], Wf[0][kt], gh0, 0, 0, 0);
                gh1 = __builtin_amdgcn_mfma_f32_16x16x32_bf16(Af[kt], Wf[1][kt], gh1, 0, 0, 0);
                gh2 = __builtin_amdgcn_mfma_f32_16x16x32_bf16(Af[kt], Wf[2][kt], gh2, 0, 0, 0);
            }
        }
        if (g && do_post) {
            #pragma unroll
            for (int kt = 0; kt < 4; ++kt)
                xacc = __builtin_amdgcn_mfma_f32_16x16x32_bf16(Af[kt], Xf[kt], xacc, 0, 0, 0);
            // beta cell values for step n-1 -> partial sums over e (this wave's 16 e's)
            float dp[4];
            #pragma unroll
            for (int r = 0; r < 4; ++r) dp[r] = tanh2(xacc[r] + bbetL) * ev[r] * wo;
            #pragma unroll
            for (int r = 0; r < 4; ++r) {
                dp[r] += __shfl_xor(dp[r], 1);
                dp[r] += __shfl_xor(dp[r], 2);
                dp[r] += __shfl_xor(dp[r], 4);
                dp[r] += __shfl_xor(dp[r], 8);
            }
            if (lr == 0) {
                #pragma unroll
                for (int r = 0; r < 4; ++r) red[rb][w][lo * 4 + r] = dp[r];
            }
        }

        // ---- gates: H_n = GRU(H_{n-1}, x_{i-n}) ----
        if (do_gate) {
            float sp[4];
            #pragma unroll
            for (int r = 0; r < 4; ++r) {
                f32x4 gv = giv[r];
                float rr = sigm2(gv[0] + gh0[r]);
                float zz = sigm2(gv[1] + gh1[r]);
                float nn = tanh2(gv[2] + rr * gh2[r]);
                float h = nn + zz * (h_old[r] - nn);
                h_old[r] = h;
                int c = lo * 4 + r;
                Hbf[wb][c][u ^ ((c & 7) * 8)] = f2bf(h);
                sp[r] = h * waL;
            }
            if (!g) { // alpha score partials for step n
                #pragma unroll
                for (int r = 0; r < 4; ++r) {
                    sp[r] += __shfl_xor(sp[r], 1);
                    sp[r] += __shfl_xor(sp[r], 2);
                    sp[r] += __shfl_xor(sp[r], 4);
                    sp[r] += __shfl_xor(sp[r], 8);
                }
                if (lr == 0) {
                    #pragma unroll
                    for (int r = 0; r < 4; ++r) red[rb][w][lo * 4 + r] = sp[r];
                }
            }
        }

        __syncthreads();
    }
}

// ---------------- reduce: out[b,i] = sum_k p*d / sum_k p + b_out ----------------
__global__ __launch_bounds__(512) void reduce_out(const float* __restrict__ p_g, const float* __restrict__ d_g,
                                                  const int* __restrict__ lengths, const float* __restrict__ b_out,
                                                  float* __restrict__ out) {
    const int w = threadIdx.x >> 6, l = threadIdx.x & 63;
    const int row = blockIdx.x * 8 + w; // b*64 + i
    const int b = row >> 6, i = row & 63;
    float p = (l <= i) ? p_g[(long)row * 64 + l] : 0.f;
    float d = (l <= i) ? d_g[(long)row * 64 + l] : 0.f;
    float pd = p * d;
    #pragma unroll
    for (int off = 1; off < 64; off <<= 1) {
        p += __shfl_xor(p, off);
        pd += __shfl_xor(pd, off);
    }
    if (l == 0) {
        float val = (i < lengths[b]) ? pd / p + b_out[0] : b_out[0];
        out[row] = val;
    }
}

// ---------------- launch ----------------
extern "C" void kernel_launch(void* const* d_in, const int* in_sizes, int n_in,
                              void* d_out, int out_size, void* d_ws, size_t ws_size,
                              hipStream_t stream) {
    (void)in_sizes; (void)n_in; (void)out_size; (void)ws_size;
    const float* x       = (const float*)d_in[0];
    const float* t       = (const float*)d_in[1];
    const int*   len     = (const int*)d_in[2];
    const float* Wemb    = (const float*)d_in[3];
    const float* Wih_a   = (const float*)d_in[4];
    const float* Whh_a   = (const float*)d_in[5];
    const float* bih_a   = (const float*)d_in[6];
    const float* bhh_a   = (const float*)d_in[7];
    const float* Wih_b   = (const float*)d_in[8];
    const float* Whh_b   = (const float*)d_in[9];
    const float* bih_b   = (const float*)d_in[10];
    const float* bhh_b   = (const float*)d_in[11];
    const float* w_alpha = (const float*)d_in[12];
    const float* b_alpha = (const float*)d_in[13];
    const float* W_beta  = (const float*)d_in[14];
    const float* b_beta  = (const float*)d_in[15];
    const float* W_out   = (const float*)d_in[16];
    const float* b_out   = (const float*)d_in[17];

    char* ws = (char*)d_ws;
    float*          emb     = (float*)(ws + 0);                 // 2048*128*4       = 1,048,576
    unsigned short* embbf   = (unsigned short*)(ws + 1048576);  // 2048*128*2       =   524,288
    float*          Gi3     = (float*)(ws + 1572864);           // 2048*2*128*4*4   = 8,388,608
    unsigned short* wembbf  = (unsigned short*)(ws + 9961472);  // 128*4896*2       = 1,253,376
    unsigned short* wihbf   = (unsigned short*)(ws + 11214848); // 768*128*2        =   196,608
    unsigned short* whhbf   = (unsigned short*)(ws + 11411456); // 768*128*2        =   196,608
    unsigned short* wbetabf = (unsigned short*)(ws + 11608064); // 128*128*2        =    32,768
    float*          p_g     = (float*)(ws + 11640832);          // 2048*64*4        =   524,288
    float*          d_g     = (float*)(ws + 12165120);          // 2048*64*4        =   524,288

    const int jobs = 128 * 612 + 768 * 16 + 768 * 16 + 128 * 16; // 104,960
    prep_kernel<<<(jobs + 255) / 256, 256, 0, stream>>>(Wemb, Wih_a, Wih_b, Whh_a, Whh_b, W_beta,
                                                        wembbf, wihbf, whhbf, wbetabf);
    emb_gemm<<<32, 512, 0, stream>>>(x, wembbf, emb, embbf);
    gi_gemm<<<64, 256, 0, stream>>>(embbf, wihbf, Wih_a, Wih_b, t, bih_a, bih_b, bhh_a, bhh_b, Gi3);
    retain_rec<<<256, 512, 0, stream>>>(whhbf, wbetabf, Gi3, emb, bhh_a, bhh_b,
                                        w_alpha, b_alpha, b_beta, W_out, p_g, d_g);
    reduce_out<<<256, 512, 0, stream>>>(p_g, d_g, len, b_out, (float*)d_out);
}

// Round 6
// 165.369 us; speedup vs baseline: 1.8928x; 1.7159x over previous
//
#include <hip/hip_runtime.h>
#include <hip/hip_bf16.h>

#define DEVI __device__ __forceinline__

typedef __attribute__((ext_vector_type(8))) short short8;
typedef __attribute__((ext_vector_type(8))) unsigned short ushort8;
typedef __attribute__((ext_vector_type(4))) unsigned short ushort4v;
typedef __attribute__((ext_vector_type(4))) float f32x4;

static constexpr int TT = 64, KIN = 4894, KINP = 4896, E = 128;
static constexpr float L2E = 1.4426950408889634f;

DEVI unsigned short f2bf(float f) {
    union { float f; unsigned u; } v; v.f = f;
    unsigned r = v.u + 0x7fffu + ((v.u >> 16) & 1u);
    return (unsigned short)(r >> 16);
}
// args pre-scaled by log2(e): exp(x) == exp2(x*L2E)
DEVI float sigm2(float x) { return __builtin_amdgcn_rcpf(1.f + __builtin_amdgcn_exp2f(-x)); }
DEVI float tanh2(float x) { return 1.f - 2.f * __builtin_amdgcn_rcpf(__builtin_amdgcn_exp2f(x + x) + 1.f); }

// ---------------- prep: weight casts (Wih/Whh/Wbeta pre-scaled by log2e) ----------------
__global__ void prep_kernel(const float* __restrict__ Wemb,
                            const float* __restrict__ Wih_a, const float* __restrict__ Wih_b,
                            const float* __restrict__ Whh_a, const float* __restrict__ Whh_b,
                            const float* __restrict__ Wbeta,
                            unsigned short* __restrict__ wembbf, unsigned short* __restrict__ wihbf,
                            unsigned short* __restrict__ whhbf, unsigned short* __restrict__ wbetabf) {
    int job = blockIdx.x * blockDim.x + threadIdx.x;
    const int JWE = 128 * 612, JWIH = 768 * 16, JWHH = 768 * 16, JWB = 128 * 16;
    if (job < JWE) {
        int row = job / 612, c8 = (job % 612) * 8;
        ushort8 v;
        #pragma unroll
        for (int jj = 0; jj < 8; ++jj) { int c = c8 + jj; v[jj] = (c < KIN) ? f2bf(Wemb[(long)row * KIN + c]) : (unsigned short)0; }
        *(ushort8*)(wembbf + (long)row * KINP + c8) = v;
        return;
    }
    job -= JWE;
    if (job < JWIH) {
        int g = job / 16, c8 = (job % 16) * 8;
        const float* src = (g < 384) ? (Wih_a + (long)g * 129) : (Wih_b + (long)(g - 384) * 129);
        ushort8 v;
        #pragma unroll
        for (int jj = 0; jj < 8; ++jj) v[jj] = f2bf(src[c8 + jj] * L2E);
        *(ushort8*)(wihbf + (long)g * 128 + c8) = v;
        return;
    }
    job -= JWIH;
    if (job < JWHH) {
        int g = job / 16, c8 = (job % 16) * 8;
        const float* src = (g < 384) ? (Whh_a + (long)g * 128) : (Whh_b + (long)(g - 384) * 128);
        ushort8 v;
        #pragma unroll
        for (int jj = 0; jj < 8; ++jj) v[jj] = f2bf(src[c8 + jj] * L2E);
        *(ushort8*)(whhbf + (long)g * 128 + c8) = v;
        return;
    }
    job -= JWHH;
    if (job < JWB) {
        int e = job / 16, c8 = (job % 16) * 8;
        ushort8 v;
        #pragma unroll
        for (int jj = 0; jj < 8; ++jj) v[jj] = f2bf(Wbeta[(long)e * 128 + c8 + jj] * L2E);
        *(ushort8*)(wbetabf + (long)e * 128 + c8) = v;
    }
}

// ---------------- emb partials: K-split GEMM, 512 blocks = (m-tile 0..127) x (ksplit 0..3) ----------------
// pout[ks][m][n] f32; ksplit in LOW blockIdx bits so each XCD's L2 holds only 2 Wemb k-slices.
__global__ __launch_bounds__(256) void emb_gemm(const float* __restrict__ x,
                                                const unsigned short* __restrict__ wembbf,
                                                float* __restrict__ pout) {
    const int ks = blockIdx.x & 3, m0 = (blockIdx.x >> 2) * 16;
    const int w = threadIdx.x >> 6, l = threadIdx.x & 63, lr = l & 15, lo = l >> 4;
    const int n0 = (2 * w) * 16 + lr, n1 = (2 * w + 1) * 16 + lr;
    const float* xrow = x + (long)(m0 + lr) * KIN;
    const int k0 = ks * 1216;
    const int nfull = 38; // ks<3: 1216 = 38*32; ks==3: 1246 -> 38 full + 30-col tail
    f32x4 acc0 = {0, 0, 0, 0}, acc1 = {0, 0, 0, 0};
    #pragma unroll 2
    for (int kt = 0; kt < nfull; ++kt) {
        int k = k0 + kt * 32 + lo * 8;
        float2 x0 = *(const float2*)(xrow + k);
        float2 x1 = *(const float2*)(xrow + k + 2);
        float2 x2 = *(const float2*)(xrow + k + 4);
        float2 x3 = *(const float2*)(xrow + k + 6);
        short8 a;
        a[0] = (short)f2bf(x0.x); a[1] = (short)f2bf(x0.y);
        a[2] = (short)f2bf(x1.x); a[3] = (short)f2bf(x1.y);
        a[4] = (short)f2bf(x2.x); a[5] = (short)f2bf(x2.y);
        a[6] = (short)f2bf(x3.x); a[7] = (short)f2bf(x3.y);
        short8 b0 = *(const short8*)(wembbf + (long)n0 * KINP + k);
        short8 b1 = *(const short8*)(wembbf + (long)n1 * KINP + k);
        acc0 = __builtin_amdgcn_mfma_f32_16x16x32_bf16(a, b0, acc0, 0, 0, 0);
        acc1 = __builtin_amdgcn_mfma_f32_16x16x32_bf16(a, b1, acc1, 0, 0, 0);
    }
    if (ks == 3) { // tail chunk at k=4864, 30 valid columns (wembbf zero-padded)
        int k = 4864 + lo * 8;
        short8 a;
        #pragma unroll
        for (int jj = 0; jj < 8; ++jj) { int c = k + jj; a[jj] = (c < KIN) ? (short)f2bf(xrow[c]) : (short)0; }
        short8 b0 = *(const short8*)(wembbf + (long)n0 * KINP + k);
        short8 b1 = *(const short8*)(wembbf + (long)n1 * KINP + k);
        acc0 = __builtin_amdgcn_mfma_f32_16x16x32_bf16(a, b0, acc0, 0, 0, 0);
        acc1 = __builtin_amdgcn_mfma_f32_16x16x32_bf16(a, b1, acc1, 0, 0, 0);
    }
    float* pbase = pout + (long)ks * 2048 * E;
    #pragma unroll
    for (int r = 0; r < 4; ++r) {
        int m = m0 + lo * 4 + r;
        pbase[(long)m * E + n0] = acc0[r];
        pbase[(long)m * E + n1] = acc1[r];
    }
}

// ---------------- emb_reduce: sum 4 k-split partials -> emb f32 + embbf ----------------
__global__ __launch_bounds__(256) void emb_reduce(const float* __restrict__ pout,
                                                  float* __restrict__ emb, unsigned short* __restrict__ embbf) {
    const long idx = (long)blockIdx.x * 256 + threadIdx.x; // 65536 f32x4 groups
    const long base = idx * 4;
    f32x4 s = *(const f32x4*)(pout + base);
    #pragma unroll
    for (int ks = 1; ks < 4; ++ks) {
        f32x4 v = *(const f32x4*)(pout + (long)ks * 2048 * E + base);
        s[0] += v[0]; s[1] += v[1]; s[2] += v[2]; s[3] += v[3];
    }
    *(f32x4*)(emb + base) = s;
    ushort4v h;
    #pragma unroll
    for (int jj = 0; jj < 4; ++jj) h[jj] = f2bf(s[jj]);
    *(ushort4v*)(embbf + base) = h;
}

// ---------------- Gi3 = log2e*(temb @ Wih^T + bih + bhh(r,z)), [tok][gru][u][r,z,n,pad] ----------------
__global__ __launch_bounds__(256) void gi_gemm(const unsigned short* __restrict__ embbf,
                                               const unsigned short* __restrict__ wihbf,
                                               const float* __restrict__ Wih_a, const float* __restrict__ Wih_b,
                                               const float* __restrict__ t,
                                               const float* __restrict__ bih_a, const float* __restrict__ bih_b,
                                               const float* __restrict__ bhh_a, const float* __restrict__ bhh_b,
                                               float* __restrict__ Gi3) {
    const int m0 = blockIdx.x * 16;
    const int w = threadIdx.x >> 6, l = threadIdx.x & 63, lr = l & 15, lo = l >> 4;
    f32x4 acc[12];
    #pragma unroll
    for (int nl = 0; nl < 12; ++nl) acc[nl] = (f32x4){0, 0, 0, 0};
    #pragma unroll
    for (int kt = 0; kt < 4; ++kt) {
        int k = kt * 32 + lo * 8;
        short8 a0 = *(const short8*)(embbf + (long)(m0 + lr) * E + k);
        #pragma unroll
        for (int nl = 0; nl < 12; ++nl) {
            int n = (w * 12 + nl) * 16 + lr;
            short8 bf = *(const short8*)(wihbf + (long)n * 128 + k);
            acc[nl] = __builtin_amdgcn_mfma_f32_16x16x32_bf16(a0, bf, acc[nl], 0, 0, 0);
        }
    }
    #pragma unroll
    for (int nl = 0; nl < 12; ++nl) {
        int n = (w * 12 + nl) * 16 + lr;
        int gru = (n >= 384) ? 1 : 0;
        int nn = n - gru * 384;
        int gt = nn >> 7, u = nn & 127;
        float bias = (gru ? bih_b[nn] : bih_a[nn]);
        if (gt < 2) bias += (gru ? bhh_b[nn] : bhh_a[nn]);
        float cw = (n < 384) ? Wih_a[(long)n * 129 + 128] : Wih_b[(long)(n - 384) * 129 + 128];
        #pragma unroll
        for (int r = 0; r < 4; ++r) {
            int tok = m0 + lo * 4 + r;
            Gi3[((long)(tok * 2 + gru) * 128 + u) * 4 + gt] = acc[nl][r] + (bias + t[tok] * cw) * L2E;
        }
    }
}

// ---------------- recurrence, ONE GRU per block ----------------
// 256 blocks = (i 0..63) x (q 0..1) x (g 0..1). 512 thr, 8 waves; wave w owns u-slice w*16+lr.
// Alpha blocks (g=0): GRU-a chains -> unnormalized softmax p[b,i,k] to global.
// Beta blocks (g=1): GRU-b chains -> d[b,i,k] = (tanh(Hb Wb^T + b) . emb_j . Wout) to global.
__global__ __launch_bounds__(512) __attribute__((amdgpu_waves_per_eu(2, 2)))
void retain_rec(const unsigned short* __restrict__ whhbf, const unsigned short* __restrict__ wbetabf,
                const float* __restrict__ Gi3, const float* __restrict__ emb,
                const float* __restrict__ bhh_a, const float* __restrict__ bhh_b,
                const float* __restrict__ w_alpha, const float* __restrict__ b_alpha,
                const float* __restrict__ b_beta, const float* __restrict__ Wout,
                float* __restrict__ p_g, float* __restrict__ d_g) {
    const int tid = threadIdx.x;
    const int w = tid >> 6, l = tid & 63, lr = l & 15, lo = l >> 4;
    const int i = blockIdx.x >> 2, q = (blockIdx.x >> 1) & 1, g = blockIdx.x & 1;
    const int u = w * 16 + lr;

    __shared__ __align__(16) unsigned short Hbf[2][16][128]; // [buf][c][u ^ ((c&7)*8)]
    __shared__ float red[2][8][16];                          // parity-lagged partial sums

    for (int idx = tid; idx < 2 * 16 * 128; idx += 512) (&Hbf[0][0][0])[idx] = 0; // H_{-1}=0

    short8 Wf[3][4];
    #pragma unroll
    for (int gt = 0; gt < 3; ++gt)
        #pragma unroll
        for (int kt = 0; kt < 4; ++kt)
            Wf[gt][kt] = *(const short8*)(whhbf + (long)(g * 384 + gt * 128 + u) * 128 + kt * 32 + lo * 8);

    short8 Xf[4];
    float bbetL = 0.f, wo = 0.f;
    if (g) {
        #pragma unroll
        for (int kt = 0; kt < 4; ++kt)
            Xf[kt] = *(const short8*)(wbetabf + (long)u * 128 + kt * 32 + lo * 8);
        bbetL = b_beta[u] * L2E;
        wo = Wout[u];
    } else {
        #pragma unroll
        for (int kt = 0; kt < 4; ++kt) {
            short8 z;
            #pragma unroll
            for (int jj = 0; jj < 8; ++jj) z[jj] = 0;
            Xf[kt] = z;
        }
    }

    const float bhnL = (g ? bhh_b : bhh_a)[256 + u] * L2E;
    const float waL = g ? 0.f : w_alpha[u] * L2E;
    const float balL = b_alpha[0] * L2E;

    float h_old[4] = {0, 0, 0, 0};
    __syncthreads();

    for (int n = 0; n <= i + 2; ++n) {
        const int rb = n & 1, wb = rb ^ 1;
        const bool do_gate = (n <= i);
        const bool do_post = (n >= 1) && (n <= i + 1); // step n-1 finish (alpha p / beta MFMA)

        // ---- wave0: finish previous partial sums -> global ----
        if (w == 0 && l < 16) {
            const long row = (long)(q * 16 + l) * 64 + i;
            if (!g) {
                if (do_post) {
                    float s = balL;
                    #pragma unroll
                    for (int ww = 0; ww < 8; ++ww) s += red[wb][ww][l];
                    p_g[row * 64 + (n - 1)] = __builtin_amdgcn_exp2f(s);
                }
            } else {
                if (n >= 2) {
                    float d = 0.f;
                    #pragma unroll
                    for (int ww = 0; ww < 8; ++ww) d += red[wb][ww][l];
                    d_g[row * 64 + (n - 2)] = d;
                }
            }
        }

        // ---- prefetch ----
        f32x4 giv[4];
        if (do_gate) {
            const int j = i - n;
            #pragma unroll
            for (int r = 0; r < 4; ++r) {
                int tok = (q * 16 + lo * 4 + r) * 64 + j;
                giv[r] = *(const f32x4*)(Gi3 + ((long)(tok * 2 + g) * 128 + u) * 4);
            }
        }
        float ev[4];
        if (g && do_post) {
            const int j2 = i - n + 1;
            #pragma unroll
            for (int r = 0; r < 4; ++r) {
                int tok = (q * 16 + lo * 4 + r) * 64 + j2;
                ev[r] = emb[(long)tok * E + u];
            }
        }

        // ---- A-fragments from swizzled LDS (H_{n-1}) ----
        short8 Af[4];
        if (do_gate || (g && do_post)) {
            #pragma unroll
            for (int kt = 0; kt < 4; ++kt) {
                int sw = (kt * 32 + lo * 8) ^ ((lr & 7) * 8);
                Af[kt] = *(const short8*)(&Hbf[rb][lr][sw]);
            }
        }

        // ---- MFMA ----
        f32x4 gh0 = {0, 0, 0, 0}, gh1 = {0, 0, 0, 0}, gh2 = {bhnL, bhnL, bhnL, bhnL};
        f32x4 xacc = {0, 0, 0, 0};
        if (do_gate) {
            #pragma unroll
            for (int kt = 0; kt < 4; ++kt) {
                gh0 = __builtin_amdgcn_mfma_f32_16x16x32_bf16(Af[kt], Wf[0][kt], gh0, 0, 0, 0);
                gh1 = __builtin_amdgcn_mfma_f32_16x16x32_bf16(Af[kt], Wf[1][kt], gh1, 0, 0, 0);
                gh2 = __builtin_amdgcn_mfma_f32_16x16x32_bf16(Af[kt], Wf[2][kt], gh2, 0, 0, 0);
            }
        }
        if (g && do_post) {
            #pragma unroll
            for (int kt = 0; kt < 4; ++kt)
                xacc = __builtin_amdgcn_mfma_f32_16x16x32_bf16(Af[kt], Xf[kt], xacc, 0, 0, 0);
            float dp[4];
            #pragma unroll
            for (int r = 0; r < 4; ++r) dp[r] = tanh2(xacc[r] + bbetL) * ev[r] * wo;
            #pragma unroll
            for (int r = 0; r < 4; ++r) {
                dp[r] += __shfl_xor(dp[r], 1);
                dp[r] += __shfl_xor(dp[r], 2);
                dp[r] += __shfl_xor(dp[r], 4);
                dp[r] += __shfl_xor(dp[r], 8);
            }
            if (lr == 0) {
                #pragma unroll
                for (int r = 0; r < 4; ++r) red[rb][w][lo * 4 + r] = dp[r];
            }
        }

        // ---- gates: H_n = GRU(H_{n-1}, x_{i-n}) ----
        if (do_gate) {
            float sp[4];
            #pragma unroll
            for (int r = 0; r < 4; ++r) {
                f32x4 gv = giv[r];
                float rr = sigm2(gv[0] + gh0[r]);
                float zz = sigm2(gv[1] + gh1[r]);
                float nn = tanh2(gv[2] + rr * gh2[r]);
                float h = nn + zz * (h_old[r] - nn);
                h_old[r] = h;
                int c = lo * 4 + r;
                Hbf[wb][c][u ^ ((c & 7) * 8)] = f2bf(h);
                sp[r] = h * waL;
            }
            if (!g) {
                #pragma unroll
                for (int r = 0; r < 4; ++r) {
                    sp[r] += __shfl_xor(sp[r], 1);
                    sp[r] += __shfl_xor(sp[r], 2);
                    sp[r] += __shfl_xor(sp[r], 4);
                    sp[r] += __shfl_xor(sp[r], 8);
                }
                if (lr == 0) {
                    #pragma unroll
                    for (int r = 0; r < 4; ++r) red[rb][w][lo * 4 + r] = sp[r];
                }
            }
        }

        __syncthreads();
    }
}

// ---------------- reduce: out[b,i] = sum_k p*d / sum_k p + b_out ----------------
__global__ __launch_bounds__(512) void reduce_out(const float* __restrict__ p_g, const float* __restrict__ d_g,
                                                  const int* __restrict__ lengths, const float* __restrict__ b_out,
                                                  float* __restrict__ out) {
    const int w = threadIdx.x >> 6, l = threadIdx.x & 63;
    const int row = blockIdx.x * 8 + w; // b*64 + i
    const int b = row >> 6, i = row & 63;
    float p = (l <= i) ? p_g[(long)row * 64 + l] : 0.f;
    float d = (l <= i) ? d_g[(long)row * 64 + l] : 0.f;
    float pd = p * d;
    #pragma unroll
    for (int off = 1; off < 64; off <<= 1) {
        p += __shfl_xor(p, off);
        pd += __shfl_xor(pd, off);
    }
    if (l == 0) {
        float val = (i < lengths[b]) ? pd / p + b_out[0] : b_out[0];
        out[row] = val;
    }
}

// ---------------- launch ----------------
extern "C" void kernel_launch(void* const* d_in, const int* in_sizes, int n_in,
                              void* d_out, int out_size, void* d_ws, size_t ws_size,
                              hipStream_t stream) {
    (void)in_sizes; (void)n_in; (void)out_size; (void)ws_size;
    const float* x       = (const float*)d_in[0];
    const float* t       = (const float*)d_in[1];
    const int*   len     = (const int*)d_in[2];
    const float* Wemb    = (const float*)d_in[3];
    const float* Wih_a   = (const float*)d_in[4];
    const float* Whh_a   = (const float*)d_in[5];
    const float* bih_a   = (const float*)d_in[6];
    const float* bhh_a   = (const float*)d_in[7];
    const float* Wih_b   = (const float*)d_in[8];
    const float* Whh_b   = (const float*)d_in[9];
    const float* bih_b   = (const float*)d_in[10];
    const float* bhh_b   = (const float*)d_in[11];
    const float* w_alpha = (const float*)d_in[12];
    const float* b_alpha = (const float*)d_in[13];
    const float* W_beta  = (const float*)d_in[14];
    const float* b_beta  = (const float*)d_in[15];
    const float* W_out   = (const float*)d_in[16];
    const float* b_out   = (const float*)d_in[17];

    char* ws = (char*)d_ws;
    float*          emb     = (float*)(ws + 0);                 // 2048*128*4       = 1,048,576
    unsigned short* embbf   = (unsigned short*)(ws + 1048576);  // 2048*128*2       =   524,288
    float*          Gi3     = (float*)(ws + 1572864);           // 2048*2*128*4*4   = 8,388,608
    unsigned short* wembbf  = (unsigned short*)(ws + 9961472);  // 128*4896*2       = 1,253,376
    unsigned short* wihbf   = (unsigned short*)(ws + 11214848); // 768*128*2        =   196,608
    unsigned short* whhbf   = (unsigned short*)(ws + 11411456); // 768*128*2        =   196,608
    unsigned short* wbetabf = (unsigned short*)(ws + 11608064); // 128*128*2        =    32,768
    float*          p_g     = (float*)(ws + 11640832);          // 2048*64*4        =   524,288
    float*          d_g     = (float*)(ws + 12165120);          // 2048*64*4        =   524,288
    float*          pout    = (float*)(ws + 12689408);          // 4*2048*128*4     = 4,194,304

    const int jobs = 128 * 612 + 768 * 16 + 768 * 16 + 128 * 16; // 104,960
    prep_kernel<<<(jobs + 255) / 256, 256, 0, stream>>>(Wemb, Wih_a, Wih_b, Whh_a, Whh_b, W_beta,
                                                        wembbf, wihbf, whhbf, wbetabf);
    emb_gemm<<<512, 256, 0, stream>>>(x, wembbf, pout);
    emb_reduce<<<256, 256, 0, stream>>>(pout, emb, embbf);
    gi_gemm<<<128, 256, 0, stream>>>(embbf, wihbf, Wih_a, Wih_b, t, bih_a, bih_b, bhh_a, bhh_b, Gi3);
    retain_rec<<<256, 512, 0, stream>>>(whhbf, wbetabf, Gi3, emb, bhh_a, bhh_b,
                                        w_alpha, b_alpha, b_beta, W_out, p_g, d_g);
    reduce_out<<<256, 512, 0, stream>>>(p_g, d_g, len, b_out, (float*)d_out);
}

// Round 8
// 160.312 us; speedup vs baseline: 1.9525x; 1.0315x over previous
//
#include <hip/hip_runtime.h>
#include <hip/hip_bf16.h>

#define DEVI __device__ __forceinline__

typedef __attribute__((ext_vector_type(8))) short short8;
typedef __attribute__((ext_vector_type(8))) unsigned short ushort8;
typedef __attribute__((ext_vector_type(4))) unsigned short ushort4v;
typedef __attribute__((ext_vector_type(4))) float f32x4;

static constexpr int TT = 64, KIN = 4894, KINP = 4896, E = 128;
static constexpr float L2E = 1.4426950408889634f;

DEVI unsigned short f2bf(float f) {
    union { float f; unsigned u; } v; v.f = f;
    unsigned r = v.u + 0x7fffu + ((v.u >> 16) & 1u);
    return (unsigned short)(r >> 16);
}
// args pre-scaled by log2(e): exp(x) == exp2(x*L2E)
DEVI float sigm2(float x) { return __builtin_amdgcn_rcpf(1.f + __builtin_amdgcn_exp2f(-x)); }
DEVI float tanh2(float x) { return 1.f - 2.f * __builtin_amdgcn_rcpf(__builtin_amdgcn_exp2f(x + x) + 1.f); }

// ---------------- prep: weight casts (Wih/Whh/Wbeta pre-scaled by log2e) ----------------
__global__ void prep_kernel(const float* __restrict__ Wemb,
                            const float* __restrict__ Wih_a, const float* __restrict__ Wih_b,
                            const float* __restrict__ Whh_a, const float* __restrict__ Whh_b,
                            const float* __restrict__ Wbeta,
                            unsigned short* __restrict__ wembbf, unsigned short* __restrict__ wihbf,
                            unsigned short* __restrict__ whhbf, unsigned short* __restrict__ wbetabf) {
    int job = blockIdx.x * blockDim.x + threadIdx.x;
    const int JWE = 128 * 612, JWIH = 768 * 16, JWHH = 768 * 16, JWB = 128 * 16;
    if (job < JWE) {
        int row = job / 612, c8 = (job % 612) * 8;
        ushort8 v;
        #pragma unroll
        for (int jj = 0; jj < 8; ++jj) { int c = c8 + jj; v[jj] = (c < KIN) ? f2bf(Wemb[(long)row * KIN + c]) : (unsigned short)0; }
        *(ushort8*)(wembbf + (long)row * KINP + c8) = v;
        return;
    }
    job -= JWE;
    if (job < JWIH) {
        int g = job / 16, c8 = (job % 16) * 8;
        const float* src = (g < 384) ? (Wih_a + (long)g * 129) : (Wih_b + (long)(g - 384) * 129);
        ushort8 v;
        #pragma unroll
        for (int jj = 0; jj < 8; ++jj) v[jj] = f2bf(src[c8 + jj] * L2E);
        *(ushort8*)(wihbf + (long)g * 128 + c8) = v;
        return;
    }
    job -= JWIH;
    if (job < JWHH) {
        int g = job / 16, c8 = (job % 16) * 8;
        const float* src = (g < 384) ? (Whh_a + (long)g * 128) : (Whh_b + (long)(g - 384) * 128);
        ushort8 v;
        #pragma unroll
        for (int jj = 0; jj < 8; ++jj) v[jj] = f2bf(src[c8 + jj] * L2E);
        *(ushort8*)(whhbf + (long)g * 128 + c8) = v;
        return;
    }
    job -= JWHH;
    if (job < JWB) {
        int e = job / 16, c8 = (job % 16) * 8;
        ushort8 v;
        #pragma unroll
        for (int jj = 0; jj < 8; ++jj) v[jj] = f2bf(Wbeta[(long)e * 128 + c8 + jj] * L2E);
        *(ushort8*)(wbetabf + (long)e * 128 + c8) = v;
    }
}

// ---------------- emb partials: K-split GEMM, 512 blocks = (m-tile 0..127) x (ksplit 0..3) ----------------
__global__ __launch_bounds__(256) void emb_gemm(const float* __restrict__ x,
                                                const unsigned short* __restrict__ wembbf,
                                                float* __restrict__ pout) {
    const int ks = blockIdx.x & 3, m0 = (blockIdx.x >> 2) * 16;
    const int w = threadIdx.x >> 6, l = threadIdx.x & 63, lr = l & 15, lo = l >> 4;
    const int n0 = (2 * w) * 16 + lr, n1 = (2 * w + 1) * 16 + lr;
    const float* xrow = x + (long)(m0 + lr) * KIN;
    const int k0 = ks * 1216;
    const int nfull = 38;
    f32x4 acc0 = {0, 0, 0, 0}, acc1 = {0, 0, 0, 0};
    #pragma unroll 2
    for (int kt = 0; kt < nfull; ++kt) {
        int k = k0 + kt * 32 + lo * 8;
        float2 x0 = *(const float2*)(xrow + k);
        float2 x1 = *(const float2*)(xrow + k + 2);
        float2 x2 = *(const float2*)(xrow + k + 4);
        float2 x3 = *(const float2*)(xrow + k + 6);
        short8 a;
        a[0] = (short)f2bf(x0.x); a[1] = (short)f2bf(x0.y);
        a[2] = (short)f2bf(x1.x); a[3] = (short)f2bf(x1.y);
        a[4] = (short)f2bf(x2.x); a[5] = (short)f2bf(x2.y);
        a[6] = (short)f2bf(x3.x); a[7] = (short)f2bf(x3.y);
        short8 b0 = *(const short8*)(wembbf + (long)n0 * KINP + k);
        short8 b1 = *(const short8*)(wembbf + (long)n1 * KINP + k);
        acc0 = __builtin_amdgcn_mfma_f32_16x16x32_bf16(a, b0, acc0, 0, 0, 0);
        acc1 = __builtin_amdgcn_mfma_f32_16x16x32_bf16(a, b1, acc1, 0, 0, 0);
    }
    if (ks == 3) {
        int k = 4864 + lo * 8;
        short8 a;
        #pragma unroll
        for (int jj = 0; jj < 8; ++jj) { int c = k + jj; a[jj] = (c < KIN) ? (short)f2bf(xrow[c]) : (short)0; }
        short8 b0 = *(const short8*)(wembbf + (long)n0 * KINP + k);
        short8 b1 = *(const short8*)(wembbf + (long)n1 * KINP + k);
        acc0 = __builtin_amdgcn_mfma_f32_16x16x32_bf16(a, b0, acc0, 0, 0, 0);
        acc1 = __builtin_amdgcn_mfma_f32_16x16x32_bf16(a, b1, acc1, 0, 0, 0);
    }
    float* pbase = pout + (long)ks * 2048 * E;
    #pragma unroll
    for (int r = 0; r < 4; ++r) {
        int m = m0 + lo * 4 + r;
        pbase[(long)m * E + n0] = acc0[r];
        pbase[(long)m * E + n1] = acc1[r];
    }
}

// ---------------- emb_reduce: sum 4 k-split partials -> emb f32 + embbf ----------------
__global__ __launch_bounds__(256) void emb_reduce(const float* __restrict__ pout,
                                                  float* __restrict__ emb, unsigned short* __restrict__ embbf) {
    const long idx = (long)blockIdx.x * 256 + threadIdx.x;
    const long base = idx * 4;
    f32x4 s = *(const f32x4*)(pout + base);
    #pragma unroll
    for (int ks = 1; ks < 4; ++ks) {
        f32x4 v = *(const f32x4*)(pout + (long)ks * 2048 * E + base);
        s[0] += v[0]; s[1] += v[1]; s[2] += v[2]; s[3] += v[3];
    }
    *(f32x4*)(emb + base) = s;
    ushort4v h;
    #pragma unroll
    for (int jj = 0; jj < 4; ++jj) h[jj] = f2bf(s[jj]);
    *(ushort4v*)(embbf + base) = h;
}

// ---------------- Gi3 = log2e*(temb @ Wih^T + bih + bhh(r,z)), [tok][gru][u][r,z,n,pad] ----------------
__global__ __launch_bounds__(256) void gi_gemm(const unsigned short* __restrict__ embbf,
                                               const unsigned short* __restrict__ wihbf,
                                               const float* __restrict__ Wih_a, const float* __restrict__ Wih_b,
                                               const float* __restrict__ t,
                                               const float* __restrict__ bih_a, const float* __restrict__ bih_b,
                                               const float* __restrict__ bhh_a, const float* __restrict__ bhh_b,
                                               float* __restrict__ Gi3) {
    const int m0 = blockIdx.x * 16;
    const int w = threadIdx.x >> 6, l = threadIdx.x & 63, lr = l & 15, lo = l >> 4;
    f32x4 acc[12];
    #pragma unroll
    for (int nl = 0; nl < 12; ++nl) acc[nl] = (f32x4){0, 0, 0, 0};
    #pragma unroll
    for (int kt = 0; kt < 4; ++kt) {
        int k = kt * 32 + lo * 8;
        short8 a0 = *(const short8*)(embbf + (long)(m0 + lr) * E + k);
        #pragma unroll
        for (int nl = 0; nl < 12; ++nl) {
            int n = (w * 12 + nl) * 16 + lr;
            short8 bf = *(const short8*)(wihbf + (long)n * 128 + k);
            acc[nl] = __builtin_amdgcn_mfma_f32_16x16x32_bf16(a0, bf, acc[nl], 0, 0, 0);
        }
    }
    #pragma unroll
    for (int nl = 0; nl < 12; ++nl) {
        int n = (w * 12 + nl) * 16 + lr;
        int gru = (n >= 384) ? 1 : 0;
        int nn = n - gru * 384;
        int gt = nn >> 7, u = nn & 127;
        float bias = (gru ? bih_b[nn] : bih_a[nn]);
        if (gt < 2) bias += (gru ? bhh_b[nn] : bhh_a[nn]);
        float cw = (n < 384) ? Wih_a[(long)n * 129 + 128] : Wih_b[(long)(n - 384) * 129 + 128];
        #pragma unroll
        for (int r = 0; r < 4; ++r) {
            int tok = m0 + lo * 4 + r;
            Gi3[((long)(tok * 2 + gru) * 128 + u) * 4 + gt] = acc[nl][r] + (bias + t[tok] * cw) * L2E;
        }
    }
}

// ---------------- recurrence, ONE GRU per block ----------------
// 256 blocks = (i 0..63) x (q 0..1) x (g 0..1). 512 thr, 8 waves; wave w owns u-slice w*16+lr.
// De-stall: (a) p/d buffered in LDS (pd_s), dumped once after the loop; (b) Gi3/emb loads
// software-pipelined one iteration ahead. ev invariant: at iter n the post-phase consumes
// token j2 = i-n+1, so the rotation at end of iter n loads token i-n and runs for n <= i
// (round-7 bug: guard was n < i, leaving the final step's ev one token stale).
__global__ __launch_bounds__(512) __attribute__((amdgpu_waves_per_eu(2, 2)))
void retain_rec(const unsigned short* __restrict__ whhbf, const unsigned short* __restrict__ wbetabf,
                const float* __restrict__ Gi3, const float* __restrict__ emb,
                const float* __restrict__ bhh_a, const float* __restrict__ bhh_b,
                const float* __restrict__ w_alpha, const float* __restrict__ b_alpha,
                const float* __restrict__ b_beta, const float* __restrict__ Wout,
                float* __restrict__ p_g, float* __restrict__ d_g) {
    const int tid = threadIdx.x;
    const int w = tid >> 6, l = tid & 63, lr = l & 15, lo = l >> 4;
    const int i = blockIdx.x >> 2, q = (blockIdx.x >> 1) & 1, g = blockIdx.x & 1;
    const int u = w * 16 + lr;

    __shared__ __align__(16) unsigned short Hbf[2][16][128]; // [buf][c][u ^ ((c&7)*8)]
    __shared__ float red[2][8][16];                          // parity-lagged partial sums
    __shared__ float pd_s[16][66];                           // per-step p (alpha) / d (beta)

    for (int idx = tid; idx < 2 * 16 * 128; idx += 512) (&Hbf[0][0][0])[idx] = 0; // H_{-1}=0

    short8 Wf[3][4];
    #pragma unroll
    for (int gt = 0; gt < 3; ++gt)
        #pragma unroll
        for (int kt = 0; kt < 4; ++kt)
            Wf[gt][kt] = *(const short8*)(whhbf + (long)(g * 384 + gt * 128 + u) * 128 + kt * 32 + lo * 8);

    short8 Xf[4];
    float bbetL = 0.f, wo = 0.f;
    if (g) {
        #pragma unroll
        for (int kt = 0; kt < 4; ++kt)
            Xf[kt] = *(const short8*)(wbetabf + (long)u * 128 + kt * 32 + lo * 8);
        bbetL = b_beta[u] * L2E;
        wo = Wout[u];
    } else {
        #pragma unroll
        for (int kt = 0; kt < 4; ++kt) {
            short8 z;
            #pragma unroll
            for (int jj = 0; jj < 8; ++jj) z[jj] = 0;
            Xf[kt] = z;
        }
    }

    const float bhnL = (g ? bhh_b : bhh_a)[256 + u] * L2E;
    const float waL = g ? 0.f : w_alpha[u] * L2E;
    const float balL = b_alpha[0] * L2E;

    float h_old[4] = {0, 0, 0, 0};

    // ---- prefetch preload: giv for iter 0 (j=i); ev for iter 1's post (j2=i) ----
    f32x4 giv[4];
    #pragma unroll
    for (int r = 0; r < 4; ++r) {
        int tok = (q * 16 + lo * 4 + r) * 64 + i;
        giv[r] = *(const f32x4*)(Gi3 + ((long)(tok * 2 + g) * 128 + u) * 4);
    }
    float ev[4] = {0, 0, 0, 0};
    if (g) {
        #pragma unroll
        for (int r = 0; r < 4; ++r) {
            int tok = (q * 16 + lo * 4 + r) * 64 + i;
            ev[r] = emb[(long)tok * E + u];
        }
    }

    __syncthreads();

    const int iend = i + 1 + g; // alpha's last p-write at n=i+1; beta's last d-write at n=i+2
    for (int n = 0; n <= iend; ++n) {
        const int rb = n & 1, wb = rb ^ 1;
        const bool do_gate = (n <= i);
        const bool do_post = (n >= 1) && (n <= i + 1);

        // ---- issue NEXT-iteration global loads (consumed next iter) ----
        f32x4 givn[4];
        float evn[4];
        const bool ld_gi = (n < i);
        const bool ld_ev = g && (n <= i); // iter n+1's post consumes token i-n
        if (ld_gi) {
            const int jn = i - n - 1;
            #pragma unroll
            for (int r = 0; r < 4; ++r) {
                int tok = (q * 16 + lo * 4 + r) * 64 + jn;
                givn[r] = *(const f32x4*)(Gi3 + ((long)(tok * 2 + g) * 128 + u) * 4);
            }
        }
        if (ld_ev) {
            const int j2n = i - n;
            #pragma unroll
            for (int r = 0; r < 4; ++r) {
                int tok = (q * 16 + lo * 4 + r) * 64 + j2n;
                evn[r] = emb[(long)tok * E + u];
            }
        }

        // ---- wave0: finish previous partial sums -> pd_s (LDS; no global store in loop) ----
        if (w == 0 && l < 16) {
            if (!g) {
                if (do_post) {
                    float s = balL;
                    #pragma unroll
                    for (int ww = 0; ww < 8; ++ww) s += red[wb][ww][l];
                    pd_s[l][n - 1] = __builtin_amdgcn_exp2f(s);
                }
            } else {
                if (n >= 2) {
                    float d = 0.f;
                    #pragma unroll
                    for (int ww = 0; ww < 8; ++ww) d += red[wb][ww][l];
                    pd_s[l][n - 2] = d;
                }
            }
        }

        // ---- A-fragments from swizzled LDS (H_{n-1}) ----
        short8 Af[4];
        if (do_gate || (g && do_post)) {
            #pragma unroll
            for (int kt = 0; kt < 4; ++kt) {
                int sw = (kt * 32 + lo * 8) ^ ((lr & 7) * 8);
                Af[kt] = *(const short8*)(&Hbf[rb][lr][sw]);
            }
        }

        // ---- MFMA ----
        f32x4 gh0 = {0, 0, 0, 0}, gh1 = {0, 0, 0, 0}, gh2 = {bhnL, bhnL, bhnL, bhnL};
        f32x4 xacc = {0, 0, 0, 0};
        if (do_gate) {
            #pragma unroll
            for (int kt = 0; kt < 4; ++kt) {
                gh0 = __builtin_amdgcn_mfma_f32_16x16x32_bf16(Af[kt], Wf[0][kt], gh0, 0, 0, 0);
                gh1 = __builtin_amdgcn_mfma_f32_16x16x32_bf16(Af[kt], Wf[1][kt], gh1, 0, 0, 0);
                gh2 = __builtin_amdgcn_mfma_f32_16x16x32_bf16(Af[kt], Wf[2][kt], gh2, 0, 0, 0);
            }
        }
        if (g && do_post) {
            #pragma unroll
            for (int kt = 0; kt < 4; ++kt)
                xacc = __builtin_amdgcn_mfma_f32_16x16x32_bf16(Af[kt], Xf[kt], xacc, 0, 0, 0);
            float dp[4];
            #pragma unroll
            for (int r = 0; r < 4; ++r) dp[r] = tanh2(xacc[r] + bbetL) * ev[r] * wo;
            #pragma unroll
            for (int r = 0; r < 4; ++r) {
                dp[r] += __shfl_xor(dp[r], 1);
                dp[r] += __shfl_xor(dp[r], 2);
                dp[r] += __shfl_xor(dp[r], 4);
                dp[r] += __shfl_xor(dp[r], 8);
            }
            if (lr == 0) {
                #pragma unroll
                for (int r = 0; r < 4; ++r) red[rb][w][lo * 4 + r] = dp[r];
            }
        }

        // ---- gates: H_n = GRU(H_{n-1}, x_{i-n}) ----
        if (do_gate) {
            float sp[4];
            #pragma unroll
            for (int r = 0; r < 4; ++r) {
                f32x4 gv = giv[r];
                float rr = sigm2(gv[0] + gh0[r]);
                float zz = sigm2(gv[1] + gh1[r]);
                float nn = tanh2(gv[2] + rr * gh2[r]);
                float h = nn + zz * (h_old[r] - nn);
                h_old[r] = h;
                int c = lo * 4 + r;
                Hbf[wb][c][u ^ ((c & 7) * 8)] = f2bf(h);
                sp[r] = h * waL;
            }
            if (!g) {
                #pragma unroll
                for (int r = 0; r < 4; ++r) {
                    sp[r] += __shfl_xor(sp[r], 1);
                    sp[r] += __shfl_xor(sp[r], 2);
                    sp[r] += __shfl_xor(sp[r], 4);
                    sp[r] += __shfl_xor(sp[r], 8);
                }
                if (lr == 0) {
                    #pragma unroll
                    for (int r = 0; r < 4; ++r) red[rb][w][lo * 4 + r] = sp[r];
                }
            }
        }

        // ---- rotate prefetch buffers ----
        if (ld_gi) {
            #pragma unroll
            for (int r = 0; r < 4; ++r) giv[r] = givn[r];
        }
        if (ld_ev) {
            #pragma unroll
            for (int r = 0; r < 4; ++r) ev[r] = evn[r];
        }

        __syncthreads();
    }

    // ---- bulk dump p/d (steps 0..i) ----
    float* dst = g ? d_g : p_g;
    for (int idx = tid; idx < 16 * 64; idx += 512) {
        int c = idx >> 6, kk = idx & 63;
        if (kk <= i) {
            long row = (long)(q * 16 + c) * 64 + i;
            dst[row * 64 + kk] = pd_s[c][kk];
        }
    }
}

// ---------------- reduce: out[b,i] = sum_k p*d / sum_k p + b_out ----------------
__global__ __launch_bounds__(512) void reduce_out(const float* __restrict__ p_g, const float* __restrict__ d_g,
                                                  const int* __restrict__ lengths, const float* __restrict__ b_out,
                                                  float* __restrict__ out) {
    const int w = threadIdx.x >> 6, l = threadIdx.x & 63;
    const int row = blockIdx.x * 8 + w; // b*64 + i
    const int b = row >> 6, i = row & 63;
    float p = (l <= i) ? p_g[(long)row * 64 + l] : 0.f;
    float d = (l <= i) ? d_g[(long)row * 64 + l] : 0.f;
    float pd = p * d;
    #pragma unroll
    for (int off = 1; off < 64; off <<= 1) {
        p += __shfl_xor(p, off);
        pd += __shfl_xor(pd, off);
    }
    if (l == 0) {
        float val = (i < lengths[b]) ? pd / p + b_out[0] : b_out[0];
        out[row] = val;
    }
}

// ---------------- launch ----------------
extern "C" void kernel_launch(void* const* d_in, const int* in_sizes, int n_in,
                              void* d_out, int out_size, void* d_ws, size_t ws_size,
                              hipStream_t stream) {
    (void)in_sizes; (void)n_in; (void)out_size; (void)ws_size;
    const float* x       = (const float*)d_in[0];
    const float* t       = (const float*)d_in[1];
    const int*   len     = (const int*)d_in[2];
    const float* Wemb    = (const float*)d_in[3];
    const float* Wih_a   = (const float*)d_in[4];
    const float* Whh_a   = (const float*)d_in[5];
    const float* bih_a   = (const float*)d_in[6];
    const float* bhh_a   = (const float*)d_in[7];
    const float* Wih_b   = (const float*)d_in[8];
    const float* Whh_b   = (const float*)d_in[9];
    const float* bih_b   = (const float*)d_in[10];
    const float* bhh_b   = (const float*)d_in[11];
    const float* w_alpha = (const float*)d_in[12];
    const float* b_alpha = (const float*)d_in[13];
    const float* W_beta  = (const float*)d_in[14];
    const float* b_beta  = (const float*)d_in[15];
    const float* W_out   = (const float*)d_in[16];
    const float* b_out   = (const float*)d_in[17];

    char* ws = (char*)d_ws;
    float*          emb     = (float*)(ws + 0);                 // 2048*128*4       = 1,048,576
    unsigned short* embbf   = (unsigned short*)(ws + 1048576);  // 2048*128*2       =   524,288
    float*          Gi3     = (float*)(ws + 1572864);           // 2048*2*128*4*4   = 8,388,608
    unsigned short* wembbf  = (unsigned short*)(ws + 9961472);  // 128*4896*2       = 1,253,376
    unsigned short* wihbf   = (unsigned short*)(ws + 11214848); // 768*128*2        =   196,608
    unsigned short* whhbf   = (unsigned short*)(ws + 11411456); // 768*128*2        =   196,608
    unsigned short* wbetabf = (unsigned short*)(ws + 11608064); // 128*128*2        =    32,768
    float*          p_g     = (float*)(ws + 11640832);          // 2048*64*4        =   524,288
    float*          d_g     = (float*)(ws + 12165120);          // 2048*64*4        =   524,288
    float*          pout    = (float*)(ws + 12689408);          // 4*2048*128*4     = 4,194,304

    const int jobs = 128 * 612 + 768 * 16 + 768 * 16 + 128 * 16; // 104,960
    prep_kernel<<<(jobs + 255) / 256, 256, 0, stream>>>(Wemb, Wih_a, Wih_b, Whh_a, Whh_b, W_beta,
                                                        wembbf, wihbf, whhbf, wbetabf);
    emb_gemm<<<512, 256, 0, stream>>>(x, wembbf, pout);
    emb_reduce<<<256, 256, 0, stream>>>(pout, emb, embbf);
    gi_gemm<<<128, 256, 0, stream>>>(embbf, wihbf, Wih_a, Wih_b, t, bih_a, bih_b, bhh_a, bhh_b, Gi3);
    retain_rec<<<256, 512, 0, stream>>>(whhbf, wbetabf, Gi3, emb, bhh_a, bhh_b,
                                        w_alpha, b_alpha, b_beta, W_out, p_g, d_g);
    reduce_out<<<256, 512, 0, stream>>>(p_g, d_g, len, b_out, (float*)d_out);
}